// Round 12
// baseline (158.862 us; speedup 1.0000x reference)
//
#include <hip/hip_runtime.h>
#include <cstddef>

// ---------------------------------------------------------------------------
// MultiHead attention, B=4 T=1024 D=1024 N=16 DH=64, SCALE=32, causal + bias.
// Round 12: REVERT GEMMs to the measured-best R9 structures (256x64 tile,
// single 40KB LDS buffer; proj 4-wave stacked, gemm_out 512-thr 8-wave).
// The 128x128 experiments (R10/R11) were ~35us slower. attn = R9 diet.
// ---------------------------------------------------------------------------

typedef __attribute__((ext_vector_type(8))) short bf16x8;
typedef __attribute__((ext_vector_type(4))) float f32x4;

#define MFMA16(a, b, c) __builtin_amdgcn_mfma_f32_16x16x32_bf16(a, b, c, 0, 0, 0)

__device__ __forceinline__ short f2bf(float f) {
  union { float f; unsigned int i; } v; v.f = f;
  unsigned int r = v.i + 0x7FFFu + ((v.i >> 16) & 1u);  // RNE
  return (short)(r >> 16);
}

__device__ __forceinline__ float fast_exp2(float x) {
  float r;
  asm volatile("v_exp_f32 %0, %1" : "=v"(r) : "v"(x));
  return r;
}

__device__ __forceinline__ unsigned int cvt_pk_bf16(float lo, float hi) {
  unsigned int r;
  asm volatile("v_cvt_pk_bf16_f32 %0, %1, %2" : "=v"(r) : "v"(lo), "v"(hi));
  return r;
}

__device__ __forceinline__ void gload_lds16(const void* g, void* l) {
  __builtin_amdgcn_global_load_lds(
      (const __attribute__((address_space(1))) void*)g,
      (__attribute__((address_space(3))) void*)l, 16, 0, 0);
}

// ---------------------------------------------------------------------------
// Fused f32 -> bf16 conversion for all 7 tensors (one launch).
// ---------------------------------------------------------------------------
__global__ __launch_bounds__(256) void cvt_all(
    const float* __restrict__ q, const float* __restrict__ k, const float* __restrict__ v,
    const float* __restrict__ wq, const float* __restrict__ wk,
    const float* __restrict__ wv, const float* __restrict__ wo,
    short* __restrict__ qb, short* __restrict__ kb, short* __restrict__ vb,
    short* __restrict__ wqb, short* __restrict__ wkb,
    short* __restrict__ wvb, short* __restrict__ wob) {
  const int total = 16 * 1048576 / 4;  // vec4 count
  int stride = gridDim.x * blockDim.x;
  for (int i = blockIdx.x * blockDim.x + threadIdx.x; i < total; i += stride) {
    int e = i * 4;
    int chunk = e >> 20;
    const float* s;
    short* d;
    int off;
    if (chunk < 12) {
      if (chunk < 4)      { s = q; d = qb; }
      else if (chunk < 8) { s = k; d = kb; }
      else                { s = v; d = vb; }
      off = e & (4 * 1048576 - 1);
    } else {
      int w = chunk - 12;
      if (w == 0)      { s = wq; d = wqb; }
      else if (w == 1) { s = wk; d = wkb; }
      else if (w == 2) { s = wv; d = wvb; }
      else             { s = wo; d = wob; }
      off = e & (1048576 - 1);
    }
    float4 x = *(const float4*)(s + off);
    short4 o;
    o.x = f2bf(x.x); o.y = f2bf(x.y); o.z = f2bf(x.z); o.w = f2bf(x.w);
    *(short4*)(d + off) = o;
  }
}

// ---------------------------------------------------------------------------
// Fused Q/K/V projection: 256x64 tile, 4 waves stacked (64 rows each), BK=64.
// Single 40KB LDS buffer. Q,K -> [B,N,T,DH]; V -> [B,N,DH,T] via LDS repack.
// (R9 structure, REP loop removed.)
// ---------------------------------------------------------------------------
__global__ __launch_bounds__(256) void proj_qkv(
    const short* __restrict__ qA, const short* __restrict__ kA, const short* __restrict__ vA,
    const short* __restrict__ Wqb, const short* __restrict__ Wkb, const short* __restrict__ Wvb,
    const float* __restrict__ bq, const float* __restrict__ bk, const float* __restrict__ bv,
    short* __restrict__ Qh, short* __restrict__ Kh, short* __restrict__ Vth) {
  __shared__ short SMEM[256 * 64 + 64 * 64];  // As(32K) + Bs(8K); reused as Vt
  short* As = SMEM;
  short* Bs = SMEM + 256 * 64;

  const int m0 = blockIdx.x * 256;
  const int n0 = blockIdx.y * 64;
  const int z = blockIdx.z;

  const short *A, *W;
  const float* bias;
  if (z == 0)      { A = qA; W = Wqb; bias = bq; }
  else if (z == 1) { A = kA; W = Wkb; bias = bk; }
  else             { A = vA; W = Wvb; bias = bv; }

  const int tid = threadIdx.x;
  const int wid = tid >> 6, lane = tid & 63;
  const int fr = lane & 15, fq = lane >> 4;

  f32x4 acc[4][4] = {};

  for (int kt = 0; kt < 16; ++kt) {
#pragma unroll
    for (int c = 0; c < 8; ++c) {
      int pbase = c * 4096 + wid * 1024;
      int pb = pbase + lane * 16;
      int lb = pb ^ (((pb >> 7) & 7) << 4);
      int grow = lb >> 7, gcol = (lb & 127) >> 1;
      gload_lds16(A + (size_t)(m0 + grow) * 1024 + kt * 64 + gcol, (char*)As + pbase);
    }
#pragma unroll
    for (int c = 0; c < 2; ++c) {
      int pbase = c * 4096 + wid * 1024;
      int pb = pbase + lane * 16;
      int lb = pb ^ (((pb >> 7) & 7) << 4);
      int grow = lb >> 7, gcol = (lb & 127) >> 1;
      gload_lds16(W + (size_t)(n0 + grow) * 1024 + kt * 64 + gcol, (char*)Bs + pbase);
    }
    __syncthreads();
#pragma unroll
    for (int kk = 0; kk < 2; ++kk) {
      bf16x8 af[4], bg[4];
      int cb = (fq * 8 + kk * 32) * 2;
#pragma unroll
      for (int m = 0; m < 4; ++m) {
        int r = wid * 64 + m * 16 + fr;
        af[m] = *(const bf16x8*)((const char*)As + (((r << 7) + cb) ^ ((r & 7) << 4)));
      }
#pragma unroll
      for (int n = 0; n < 4; ++n) {
        int r = n * 16 + fr;
        bg[n] = *(const bf16x8*)((const char*)Bs + (((r << 7) + cb) ^ ((r & 7) << 4)));
      }
#pragma unroll
      for (int m = 0; m < 4; ++m)
#pragma unroll
        for (int n = 0; n < 4; ++n)
          acc[m][n] = MFMA16(af[m], bg[n], acc[m][n]);
    }
    __syncthreads();
  }

  if (z < 2) {
    short* dst = (z == 0) ? Qh : Kh;
#pragma unroll
    for (int m = 0; m < 4; ++m)
#pragma unroll
      for (int n = 0; n < 4; ++n) {
        int col = n0 + n * 16 + fr;
        float bval = bias[col];
        int row0 = m0 + wid * 64 + m * 16 + fq * 4;
        int hh = col >> 6, dh = col & 63;
#pragma unroll
        for (int j = 0; j < 4; ++j) {
          int row = row0 + j;
          int bb = row >> 10, t = row & 1023;
          dst[(((size_t)(bb * 16 + hh)) * 1024 + t) * 64 + dh] = f2bf(acc[m][n][j] + bval);
        }
      }
  } else {
    short* Vt = SMEM;  // [64][264] shorts (33.8 KB <= 40 KB)
#pragma unroll
    for (int m = 0; m < 4; ++m)
#pragma unroll
      for (int n = 0; n < 4; ++n) {
        int coll = n * 16 + fr;
        float bval = bias[n0 + coll];
        int rowl0 = wid * 64 + m * 16 + fq * 4;
#pragma unroll
        for (int j = 0; j < 4; ++j)
          Vt[coll * 264 + rowl0 + j] = f2bf(acc[m][n][j] + bval);
      }
    __syncthreads();
    const int bb = m0 >> 10, t0 = m0 & 1023;
#pragma unroll
    for (int it = 0; it < 8; ++it) {
      int qq = tid + it * 256;          // 0..2047 : (64 rows) x (32 x 16B)
      int rowl = qq >> 5, seg = qq & 31;
      bf16x8 vv = *(const bf16x8*)&Vt[rowl * 264 + seg * 8];
      int cg = n0 + rowl, hh = cg >> 6, dh = cg & 63;
      *(bf16x8*)&Vth[(((size_t)(bb * 16 + hh)) * 64 + dh) * 1024 + t0 + seg * 8] = vv;
    }
  }
}

// ---------------------------------------------------------------------------
// Output projection: 512 thr / 8 waves, 256x64 tile (R9 structure).
// ---------------------------------------------------------------------------
__global__ __launch_bounds__(512) void gemm_out(const short* __restrict__ A,
                                                const short* __restrict__ W,
                                                const float* __restrict__ bias,
                                                float* __restrict__ C) {
  __shared__ short As[256 * 64];
  __shared__ short Bs[64 * 64];
  const int m0 = blockIdx.x * 256;
  const int n0 = blockIdx.y * 64;

  const int tid = threadIdx.x;
  const int wid = tid >> 6, lane = tid & 63;
  const int fr = lane & 15, fq = lane >> 4;

  f32x4 acc[2][4] = {};

  for (int kt = 0; kt < 16; ++kt) {
#pragma unroll
    for (int c = 0; c < 4; ++c) {
      int pbase = c * 8192 + wid * 1024;
      int pb = pbase + lane * 16;
      int lb = pb ^ (((pb >> 7) & 7) << 4);
      int grow = lb >> 7, gcol = (lb & 127) >> 1;
      gload_lds16(A + (size_t)(m0 + grow) * 1024 + kt * 64 + gcol, (char*)As + pbase);
    }
    {
      int pbase = wid * 1024;
      int pb = pbase + lane * 16;
      int lb = pb ^ (((pb >> 7) & 7) << 4);
      int grow = lb >> 7, gcol = (lb & 127) >> 1;
      gload_lds16(W + (size_t)(n0 + grow) * 1024 + kt * 64 + gcol, (char*)Bs + pbase);
    }
    __syncthreads();
#pragma unroll
    for (int kk = 0; kk < 2; ++kk) {
      bf16x8 af[2], bg[4];
      int cb = (fq * 8 + kk * 32) * 2;
#pragma unroll
      for (int m = 0; m < 2; ++m) {
        int r = wid * 32 + m * 16 + fr;
        af[m] = *(const bf16x8*)((const char*)As + (((r << 7) + cb) ^ ((r & 7) << 4)));
      }
#pragma unroll
      for (int n = 0; n < 4; ++n) {
        int r = n * 16 + fr;
        bg[n] = *(const bf16x8*)((const char*)Bs + (((r << 7) + cb) ^ ((r & 7) << 4)));
      }
#pragma unroll
      for (int m = 0; m < 2; ++m)
#pragma unroll
        for (int n = 0; n < 4; ++n)
          acc[m][n] = MFMA16(af[m], bg[n], acc[m][n]);
    }
    __syncthreads();
  }

#pragma unroll
  for (int m = 0; m < 2; ++m)
#pragma unroll
    for (int n = 0; n < 4; ++n) {
      int col = n0 + n * 16 + fr;
      float bval = bias[col];
      int row0 = m0 + wid * 32 + m * 16 + fq * 4;
#pragma unroll
      for (int j = 0; j < 4; ++j)
        C[(size_t)(row0 + j) * 1024 + col] = acc[m][n][j] + bval;
    }
}

// ---------------------------------------------------------------------------
// Flash attention (R9): grid (16 q-tiles, 64 heads), 4 waves, QBLK=64,
// KVBLK=64. K/V + bias double-buffered in LDS via global_load_lds; swapped
// QK^T (lane owns one q-row); log2-domain softmax (v_exp_f32), cvt_pk P-pack,
// defer-max, mask in LDS, setprio around MFMA, tree reductions.
// ---------------------------------------------------------------------------
__global__ __launch_bounds__(256) void attn_kernel(
    const short* __restrict__ Qh, const short* __restrict__ Kh,
    const short* __restrict__ Vth, const float* __restrict__ Wb,
    const float* __restrict__ mask, short* __restrict__ Aout) {
  __shared__ short Ks[2][64 * 64];    // 8 KB x2, 128B rows, ^((r&7)<<4)
  __shared__ short Vs[2][64 * 64];    // 8 KB x2 (V^T [dh][t])
  __shared__ float Bi[2][4096];       // 16 KB x2 bias tile, 256B rows, swz
  __shared__ float Ms[1024];          // mask row (staged once)
  __shared__ short Ps[4][16 * 88];    // per-wave P, stride 88

  const int tid = threadIdx.x;
  const int wid = tid >> 6, lane = tid & 63;
  const int fr = lane & 15, fq = lane >> 4;
  const int h = blockIdx.y, b = h >> 4;
  const int qi = (int)gridDim.x - 1 - (int)blockIdx.x;  // heavy tiles first
  const int q0 = qi * 64;
  const int qrow = q0 + wid * 16 + fr;  // this lane's q-row

  const short* qbase = Qh + ((size_t)h * 1024 + qrow) * 64 + fq * 8;
  bf16x8 qf0 = *(const bf16x8*)qbase;
  bf16x8 qf1 = *(const bf16x8*)(qbase + 32);

  const short* Kbase = Kh + (size_t)h * 1024 * 64;
  const short* Vbase = Vth + (size_t)h * 64 * 1024;
  const float* wbase = Wb + (size_t)h * 1024 * 1024;
  const float* mbase = mask + b * 1024;

  auto stage = [&](int buf, int k0) {
#pragma unroll
    for (int c = 0; c < 2; ++c) {  // K + V^T tiles
      int pbase = c * 4096 + wid * 1024;
      int pb = pbase + lane * 16;
      int lb = pb ^ (((pb >> 7) & 7) << 4);
      int grow = lb >> 7, gcol = (lb & 127) >> 1;
      gload_lds16(Kbase + (size_t)(k0 + grow) * 64 + gcol, (char*)Ks[buf] + pbase);
      gload_lds16(Vbase + (size_t)grow * 1024 + k0 + gcol, (char*)Vs[buf] + pbase);
    }
#pragma unroll
    for (int c = 0; c < 4; ++c) {  // bias tile (f32, 256B rows)
      int pbase = c * 4096 + wid * 1024;
      int pb = pbase + lane * 16;
      int lb = pb ^ (((pb >> 8) & 7) << 4);
      int grow = lb >> 8, gcolf = (lb & 255) >> 2;
      gload_lds16(wbase + (size_t)(q0 + grow) * 1024 + k0 + gcolf, (char*)Bi[buf] + pbase);
    }
  };

  f32x4 o_acc[4] = {};
  float m_run = -3.0e38f, l_run = 0.f;
  const float C2 = 0.045084439f;      // log2(e)/32
  const float PEN2 = 4.5084440e8f;    // 3.125e8 * log2(e)

  // prologue: mask row + first tile
  gload_lds16(mbase + wid * 256 + lane * 4, (char*)Ms + wid * 1024);
  stage(0, 0);
  __syncthreads();
  int cur = 0;

  for (int kt = 0; kt <= qi; ++kt) {
    const int k0 = kt * 64;
    if (kt < qi) stage(cur ^ 1, k0 + 64);  // async prefetch, drained at barrier
    const bool diag = (kt == qi);

    // S^T = K·Q^T
    f32x4 s_acc[4] = {};
    __builtin_amdgcn_s_setprio(1);
#pragma unroll
    for (int kk = 0; kk < 2; ++kk)
#pragma unroll
      for (int nt = 0; nt < 4; ++nt) {
        int r = nt * 16 + fr;
        int cb = fq * 16 + kk * 64;
        bf16x8 kf = *(const bf16x8*)((const char*)Ks[cur] + (((r << 7) + cb) ^ ((r & 7) << 4)));
        s_acc[nt] = MFMA16(kf, kk == 0 ? qf0 : qf1, s_acc[nt]);
      }
    __builtin_amdgcn_s_setprio(0);

    // bias + mask from LDS
    f32x4 bv[4], mkv[4];
#pragma unroll
    for (int nt = 0; nt < 4; ++nt) {
      int lbyte = (wid * 16 + fr) * 256 + nt * 64 + fq * 16;
      bv[nt] = *(const f32x4*)((const char*)Bi[cur] + (lbyte ^ ((fr & 7) << 4)));
      mkv[nt] = *(const f32x4*)&Ms[k0 + nt * 16 + fq * 4];
    }

    // logits in log2 domain
    float p[16];
#pragma unroll
    for (int nt = 0; nt < 4; ++nt)
#pragma unroll
      for (int j = 0; j < 4; ++j) {
        float s = (s_acc[nt][j] + bv[nt][j]) * C2 - (1.0f - mkv[nt][j]) * PEN2;
        if (diag && (nt * 16 + fq * 4 + j) > (wid * 16 + fr)) s = -3.0e38f;
        p[nt * 4 + j] = s;
      }

    // tree max over 16 + 2 shuffles -> row max
    float t8[8], t4[4];
#pragma unroll
    for (int i = 0; i < 8; ++i) t8[i] = fmaxf(p[i], p[i + 8]);
#pragma unroll
    for (int i = 0; i < 4; ++i) t4[i] = fmaxf(t8[i], t8[i + 4]);
    float pmax = fmaxf(fmaxf(t4[0], t4[1]), fmaxf(t4[2], t4[3]));
    pmax = fmaxf(pmax, __shfl_xor(pmax, 16));
    pmax = fmaxf(pmax, __shfl_xor(pmax, 32));

    // defer-max: rescale only when the max grew past THR (11.5 log2 ~ 8 nats)
    if (!__all(pmax - m_run <= 11.5f)) {
      float mnew = fmaxf(m_run, pmax);
      float corr = fast_exp2(m_run - mnew);
      m_run = mnew;
      l_run *= corr;
#pragma unroll
      for (int nt = 0; nt < 4; ++nt) o_acc[nt] *= corr;
    }

#pragma unroll
    for (int i = 0; i < 16; ++i) p[i] = fast_exp2(p[i] - m_run);
    float a8[8], a4[4];
#pragma unroll
    for (int i = 0; i < 8; ++i) a8[i] = p[i] + p[i + 8];
#pragma unroll
    for (int i = 0; i < 4; ++i) a4[i] = a8[i] + a8[i + 4];
    float rsum = (a4[0] + a4[1]) + (a4[2] + a4[3]);
    rsum += __shfl_xor(rsum, 16);
    rsum += __shfl_xor(rsum, 32);
    l_run += rsum;

    // P -> per-wave LDS: cvt_pk pairs, b64 writes
#pragma unroll
    for (int nt = 0; nt < 4; ++nt) {
      uint2 w2;
      w2.x = cvt_pk_bf16(p[nt * 4 + 0], p[nt * 4 + 1]);
      w2.y = cvt_pk_bf16(p[nt * 4 + 2], p[nt * 4 + 3]);
      *(uint2*)&Ps[wid][fr * 88 + nt * 16 + fq * 4] = w2;
    }
    asm volatile("s_waitcnt lgkmcnt(0)" ::: "memory");
    bf16x8 pf0 = *(const bf16x8*)&Ps[wid][fr * 88 + fq * 8];
    bf16x8 pf1 = *(const bf16x8*)&Ps[wid][fr * 88 + fq * 8 + 32];

    // O += V^T · P
    __builtin_amdgcn_s_setprio(1);
#pragma unroll
    for (int kk = 0; kk < 2; ++kk)
#pragma unroll
      for (int nt = 0; nt < 4; ++nt) {
        int r = nt * 16 + fr;
        int cb = fq * 16 + kk * 64;
        bf16x8 vf = *(const bf16x8*)((const char*)Vs[cur] + (((r << 7) + cb) ^ ((r & 7) << 4)));
        o_acc[nt] = MFMA16(vf, kk == 0 ? pf0 : pf1, o_acc[nt]);
      }
    __builtin_amdgcn_s_setprio(0);

    __syncthreads();  // all waves done with [cur]; prefetch drained
    cur ^= 1;
  }

  // normalize + write merged-head bf16 [4096][1024]
  float rl = 1.0f / l_run;
  size_t row = (size_t)(b * 1024 + q0 + wid * 16 + fr);
#pragma unroll
  for (int nt = 0; nt < 4; ++nt) {
    uint2 sv;
    sv.x = cvt_pk_bf16(o_acc[nt][0] * rl, o_acc[nt][1] * rl);
    sv.y = cvt_pk_bf16(o_acc[nt][2] * rl, o_acc[nt][3] * rl);
    int col = (h & 15) * 64 + nt * 16 + fq * 4;
    *(uint2*)&Aout[row * 1024 + col] = sv;
  }
}

// ---------------------------------------------------------------------------
extern "C" void kernel_launch(void* const* d_in, const int* in_sizes, int n_in,
                              void* d_out, int out_size, void* d_ws, size_t ws_size,
                              hipStream_t stream) {
  const float* query = (const float*)d_in[0];
  const float* key   = (const float*)d_in[1];
  const float* value = (const float*)d_in[2];
  const float* mask  = (const float*)d_in[3];
  const float* wts   = (const float*)d_in[4];
  const float* Wq    = (const float*)d_in[5];
  const float* bq    = (const float*)d_in[6];
  const float* Wk    = (const float*)d_in[7];
  const float* bk    = (const float*)d_in[8];
  const float* Wv    = (const float*)d_in[9];
  const float* bv    = (const float*)d_in[10];
  const float* Wo    = (const float*)d_in[11];
  const float* bo    = (const float*)d_in[12];

  char* ws = (char*)d_ws;
  const size_t MB = 1u << 20;
  short* qbf = (short*)(ws + 0);        // 8 MB  (reused as attn out)
  short* kbf = (short*)(ws + 8 * MB);   // 8 MB
  short* vbf = (short*)(ws + 16 * MB);  // 8 MB
  short* Wqb = (short*)(ws + 24 * MB);  // 2 MB
  short* Wkb = (short*)(ws + 26 * MB);
  short* Wvb = (short*)(ws + 28 * MB);
  short* Wob = (short*)(ws + 30 * MB);
  short* Qh  = (short*)(ws + 32 * MB);  // 8 MB [B,N,T,DH]
  short* Kh  = (short*)(ws + 40 * MB);  // 8 MB [B,N,T,DH]
  short* Vth = (short*)(ws + 48 * MB);  // 8 MB [B,N,DH,T]
  short* attnb = qbf;                   // alias: qbf dead after proj_qkv

  cvt_all<<<dim3(2048), dim3(256), 0, stream>>>(query, key, value, Wq, Wk, Wv, Wo,
                                                qbf, kbf, vbf, Wqb, Wkb, Wvb, Wob);
  proj_qkv<<<dim3(16, 16, 3), dim3(256), 0, stream>>>(qbf, kbf, vbf, Wqb, Wkb, Wvb,
                                                      bq, bk, bv, Qh, Kh, Vth);
  attn_kernel<<<dim3(16, 64), dim3(256), 0, stream>>>(Qh, Kh, Vth, wts, mask, attnb);
  gemm_out<<<dim3(16, 16), dim3(512), 0, stream>>>(attnb, Wob, bo, (float*)d_out);
}

// Round 13
// 142.226 us; speedup vs baseline: 1.1170x; 1.1170x over previous
//
#include <hip/hip_runtime.h>
#include <cstddef>

// ---------------------------------------------------------------------------
// MultiHead attention, B=4 T=1024 D=1024 N=16 DH=64, SCALE=32, causal + bias.
// Round 13: attn KVBLK=32 + LDS 37KB => 4 blocks/CU (was 2). Simple dbuf +
// one barrier/tile (R7's ring complexity avoided). Mask read from L2 per tile.
// GEMMs = R10 (128x128 dbuf, measured best). cvt unchanged.
// ---------------------------------------------------------------------------

typedef __attribute__((ext_vector_type(8))) short bf16x8;
typedef __attribute__((ext_vector_type(4))) float f32x4;

#define MFMA16(a, b, c) __builtin_amdgcn_mfma_f32_16x16x32_bf16(a, b, c, 0, 0, 0)

__device__ __forceinline__ short f2bf(float f) {
  union { float f; unsigned int i; } v; v.f = f;
  unsigned int r = v.i + 0x7FFFu + ((v.i >> 16) & 1u);  // RNE
  return (short)(r >> 16);
}

__device__ __forceinline__ float fast_exp2(float x) {
  float r;
  asm volatile("v_exp_f32 %0, %1" : "=v"(r) : "v"(x));
  return r;
}

__device__ __forceinline__ unsigned int cvt_pk_bf16(float lo, float hi) {
  unsigned int r;
  asm volatile("v_cvt_pk_bf16_f32 %0, %1, %2" : "=v"(r) : "v"(lo), "v"(hi));
  return r;
}

__device__ __forceinline__ void gload_lds16(const void* g, void* l) {
  __builtin_amdgcn_global_load_lds(
      (const __attribute__((address_space(1))) void*)g,
      (__attribute__((address_space(3))) void*)l, 16, 0, 0);
}

// ---------------------------------------------------------------------------
// Fused f32 -> bf16 conversion for all 7 tensors (one launch).
// ---------------------------------------------------------------------------
__global__ __launch_bounds__(256) void cvt_all(
    const float* __restrict__ q, const float* __restrict__ k, const float* __restrict__ v,
    const float* __restrict__ wq, const float* __restrict__ wk,
    const float* __restrict__ wv, const float* __restrict__ wo,
    short* __restrict__ qb, short* __restrict__ kb, short* __restrict__ vb,
    short* __restrict__ wqb, short* __restrict__ wkb,
    short* __restrict__ wvb, short* __restrict__ wob) {
  const int total = 16 * 1048576 / 4;  // vec4 count
  int stride = gridDim.x * blockDim.x;
  for (int i = blockIdx.x * blockDim.x + threadIdx.x; i < total; i += stride) {
    int e = i * 4;
    int chunk = e >> 20;
    const float* s;
    short* d;
    int off;
    if (chunk < 12) {
      if (chunk < 4)      { s = q; d = qb; }
      else if (chunk < 8) { s = k; d = kb; }
      else                { s = v; d = vb; }
      off = e & (4 * 1048576 - 1);
    } else {
      int w = chunk - 12;
      if (w == 0)      { s = wq; d = wqb; }
      else if (w == 1) { s = wk; d = wkb; }
      else if (w == 2) { s = wv; d = wvb; }
      else             { s = wo; d = wob; }
      off = e & (1048576 - 1);
    }
    float4 x = *(const float4*)(s + off);
    short4 o;
    o.x = f2bf(x.x); o.y = f2bf(x.y); o.z = f2bf(x.z); o.w = f2bf(x.w);
    *(short4*)(d + off) = o;
  }
}

// ---------------------------------------------------------------------------
// Fused Q/K/V projection: 128x128 tile, 4 waves (2x2), BK=64, double-buffered
// 64KB LDS, one barrier per K-step (R10, measured best).
// ---------------------------------------------------------------------------
__global__ __launch_bounds__(256) void proj_qkv(
    const short* __restrict__ qA, const short* __restrict__ kA, const short* __restrict__ vA,
    const short* __restrict__ Wqb, const short* __restrict__ Wkb, const short* __restrict__ Wvb,
    const float* __restrict__ bq, const float* __restrict__ bk, const float* __restrict__ bv,
    short* __restrict__ Qh, short* __restrict__ Kh, short* __restrict__ Vth) {
  __shared__ short DS[2][16384];  // per buf: As 8192 + Bs 8192 shorts = 32KB

  const int m0 = blockIdx.x * 128;
  const int n0 = blockIdx.y * 128;
  const int z = blockIdx.z;

  const short *A, *W;
  const float* bias;
  if (z == 0)      { A = qA; W = Wqb; bias = bq; }
  else if (z == 1) { A = kA; W = Wkb; bias = bk; }
  else             { A = vA; W = Wvb; bias = bv; }

  const int tid = threadIdx.x;
  const int wid = tid >> 6, lane = tid & 63;
  const int wr = wid >> 1, wc = wid & 1;
  const int fr = lane & 15, fq = lane >> 4;

  auto stage = [&](int buf, int kt) {
#pragma unroll
    for (int c = 0; c < 4; ++c) {
      int pbase = c * 4096 + wid * 1024;
      int pb = pbase + lane * 16;
      int lb = pb ^ (((pb >> 7) & 7) << 4);
      int grow = lb >> 7, gcol = (lb & 127) >> 1;
      gload_lds16(A + (size_t)(m0 + grow) * 1024 + kt * 64 + gcol,
                  (char*)DS[buf] + pbase);
      gload_lds16(W + (size_t)(n0 + grow) * 1024 + kt * 64 + gcol,
                  (char*)(DS[buf] + 8192) + pbase);
    }
  };

  f32x4 acc[4][4] = {};
  stage(0, 0);
  __syncthreads();
  int cur = 0;

  for (int kt = 0; kt < 16; ++kt) {
    if (kt < 15) stage(cur ^ 1, kt + 1);  // prefetch, drained by end barrier
    const short* As = DS[cur];
    const short* Bs = DS[cur] + 8192;
#pragma unroll
    for (int kk = 0; kk < 2; ++kk) {
      bf16x8 af[4], bg[4];
      int cb = (fq * 8 + kk * 32) * 2;
#pragma unroll
      for (int m = 0; m < 4; ++m) {
        int r = wr * 64 + m * 16 + fr;
        af[m] = *(const bf16x8*)((const char*)As + (((r << 7) + cb) ^ ((r & 7) << 4)));
      }
#pragma unroll
      for (int n = 0; n < 4; ++n) {
        int r = wc * 64 + n * 16 + fr;
        bg[n] = *(const bf16x8*)((const char*)Bs + (((r << 7) + cb) ^ ((r & 7) << 4)));
      }
#pragma unroll
      for (int m = 0; m < 4; ++m)
#pragma unroll
        for (int n = 0; n < 4; ++n)
          acc[m][n] = MFMA16(af[m], bg[n], acc[m][n]);
    }
    __syncthreads();  // waves done with [cur]; prefetch into [cur^1] complete
    cur ^= 1;
  }

  if (z < 2) {
    short* dst = (z == 0) ? Qh : Kh;
#pragma unroll
    for (int m = 0; m < 4; ++m)
#pragma unroll
      for (int n = 0; n < 4; ++n) {
        int col = n0 + wc * 64 + n * 16 + fr;
        float bval = bias[col];
        int row0 = m0 + wr * 64 + m * 16 + fq * 4;
        int hh = col >> 6, dh = col & 63;
#pragma unroll
        for (int j = 0; j < 4; ++j) {
          int row = row0 + j;
          int bb = row >> 10, t = row & 1023;
          dst[(((size_t)(bb * 16 + hh)) * 1024 + t) * 64 + dh] = f2bf(acc[m][n][j] + bval);
        }
      }
  } else {
    // transpose 128x128 block through LDS, then coalesced bf16x8 stores
    short* Vt = (short*)DS;  // [128 cols][136] shorts = 34.8 KB
#pragma unroll
    for (int m = 0; m < 4; ++m)
#pragma unroll
      for (int n = 0; n < 4; ++n) {
        int coll = wc * 64 + n * 16 + fr;
        float bval = bias[n0 + coll];
        int rowl0 = wr * 64 + m * 16 + fq * 4;
#pragma unroll
        for (int j = 0; j < 4; ++j)
          Vt[coll * 136 + rowl0 + j] = f2bf(acc[m][n][j] + bval);
      }
    __syncthreads();
    const int bb = m0 >> 10, t0 = m0 & 1023;
#pragma unroll
    for (int it = 0; it < 8; ++it) {
      int qq = tid + it * 256;          // 2048 chunks: 128 rows x 16 chunks
      int rowl = qq >> 4, seg = qq & 15;
      bf16x8 vv = *(const bf16x8*)&Vt[rowl * 136 + seg * 8];
      int cg = n0 + rowl, hh = cg >> 6, dh = cg & 63;
      *(bf16x8*)&Vth[(((size_t)(bb * 16 + hh)) * 64 + dh) * 1024 + t0 + seg * 8] = vv;
    }
  }
}

// ---------------------------------------------------------------------------
// Output projection: 128x128 tile, 4 waves (2x2), dbuf, one barrier per kt
// (R10, measured best). d_out f32 = A @ Wo^T + bo.
// ---------------------------------------------------------------------------
__global__ __launch_bounds__(256) void gemm_out(const short* __restrict__ A,
                                                const short* __restrict__ W,
                                                const float* __restrict__ bias,
                                                float* __restrict__ C) {
  __shared__ short DS[2][16384];

  const int m0 = blockIdx.x * 128;
  const int n0 = blockIdx.y * 128;

  const int tid = threadIdx.x;
  const int wid = tid >> 6, lane = tid & 63;
  const int wr = wid >> 1, wc = wid & 1;
  const int fr = lane & 15, fq = lane >> 4;

  auto stage = [&](int buf, int kt) {
#pragma unroll
    for (int c = 0; c < 4; ++c) {
      int pbase = c * 4096 + wid * 1024;
      int pb = pbase + lane * 16;
      int lb = pb ^ (((pb >> 7) & 7) << 4);
      int grow = lb >> 7, gcol = (lb & 127) >> 1;
      gload_lds16(A + (size_t)(m0 + grow) * 1024 + kt * 64 + gcol,
                  (char*)DS[buf] + pbase);
      gload_lds16(W + (size_t)(n0 + grow) * 1024 + kt * 64 + gcol,
                  (char*)(DS[buf] + 8192) + pbase);
    }
  };

  f32x4 acc[4][4] = {};
  stage(0, 0);
  __syncthreads();
  int cur = 0;

  for (int kt = 0; kt < 16; ++kt) {
    if (kt < 15) stage(cur ^ 1, kt + 1);
    const short* As = DS[cur];
    const short* Bs = DS[cur] + 8192;
#pragma unroll
    for (int kk = 0; kk < 2; ++kk) {
      bf16x8 af[4], bg[4];
      int cb = (fq * 8 + kk * 32) * 2;
#pragma unroll
      for (int m = 0; m < 4; ++m) {
        int r = wr * 64 + m * 16 + fr;
        af[m] = *(const bf16x8*)((const char*)As + (((r << 7) + cb) ^ ((r & 7) << 4)));
      }
#pragma unroll
      for (int n = 0; n < 4; ++n) {
        int r = wc * 64 + n * 16 + fr;
        bg[n] = *(const bf16x8*)((const char*)Bs + (((r << 7) + cb) ^ ((r & 7) << 4)));
      }
#pragma unroll
      for (int m = 0; m < 4; ++m)
#pragma unroll
        for (int n = 0; n < 4; ++n)
          acc[m][n] = MFMA16(af[m], bg[n], acc[m][n]);
    }
    __syncthreads();
    cur ^= 1;
  }

#pragma unroll
  for (int m = 0; m < 4; ++m)
#pragma unroll
    for (int n = 0; n < 4; ++n) {
      int col = n0 + wc * 64 + n * 16 + fr;
      float bval = bias[col];
      int row0 = m0 + wr * 64 + m * 16 + fq * 4;
#pragma unroll
      for (int j = 0; j < 4; ++j)
        C[(size_t)(row0 + j) * 1024 + col] = acc[m][n][j] + bval;
    }
}

// ---------------------------------------------------------------------------
// Flash attention: grid (16 q-tiles, 64 heads), 4 waves, QBLK=64, KVBLK=32.
// LDS 37KB -> 4 blocks/CU. Double-buffered K/V/bias via global_load_lds,
// one barrier per tile. Swapped QK^T (lane owns one q-row), log2 softmax,
// defer-max, cvt_pk P-pack, setprio. Mask read from L2 per tile (regs).
// ---------------------------------------------------------------------------
__global__ __launch_bounds__(256) void attn_kernel(
    const short* __restrict__ Qh, const short* __restrict__ Kh,
    const short* __restrict__ Vth, const float* __restrict__ Wb,
    const float* __restrict__ mask, short* __restrict__ Aout) {
  __shared__ short Ks[2][2048];   // [k 0..31][dh 0..63] bf16, 128B rows, ^((r&7)<<4)
  __shared__ short Vs[2][2048];   // [dh 0..63][k 0..31] bf16, 64B rows, ^(((r>>1)&3)<<4)
  __shared__ float Bi[2][2048];   // [q 0..63][k 0..31] f32, 128B rows, ^((r&7)<<4)
  __shared__ short Ps[4][16 * 40];  // per-wave P [16 q][32 k], stride 40 (80B)

  const int tid = threadIdx.x;
  const int wid = tid >> 6, lane = tid & 63;
  const int fr = lane & 15, fq = lane >> 4;
  const int h = blockIdx.y, b = h >> 4;
  const int qi = (int)gridDim.x - 1 - (int)blockIdx.x;  // heavy tiles first
  const int q0 = qi * 64;
  const int qrow = q0 + wid * 16 + fr;   // this lane's q-row
  const int NT = 2 * qi + 2;             // 32-wide KV tiles

  const short* qbase = Qh + ((size_t)h * 1024 + qrow) * 64 + fq * 8;
  bf16x8 qf0 = *(const bf16x8*)qbase;
  bf16x8 qf1 = *(const bf16x8*)(qbase + 32);

  const short* Kbase = Kh + (size_t)h * 1024 * 64;
  const short* Vbase = Vth + (size_t)h * 64 * 1024;
  const float* wbase = Wb + (size_t)h * 1024 * 1024;
  const float* mbase = mask + b * 1024;

  auto stage = [&](int buf, int kt2) {
    const int k0 = kt2 * 32;
    {  // K tile 4KB: rows k, 128B
      int pb = wid * 1024 + lane * 16;
      int lb = pb ^ (((pb >> 7) & 7) << 4);
      gload_lds16(Kbase + (size_t)(k0 + (lb >> 7)) * 64 + ((lb & 127) >> 1),
                  (char*)Ks[buf] + wid * 1024);
    }
    {  // V^T tile 4KB: rows dh, 64B, swizzle on (row>>1)&3
      int pb = wid * 1024 + lane * 16;
      int lb = pb ^ (((pb >> 7) & 3) << 4);
      gload_lds16(Vbase + (size_t)(lb >> 6) * 1024 + k0 + ((lb & 63) >> 1),
                  (char*)Vs[buf] + wid * 1024);
    }
#pragma unroll
    for (int c = 0; c < 2; ++c) {  // bias tile 8KB: rows q, 128B (32 f32)
      int pbase = c * 4096 + wid * 1024;
      int pb = pbase + lane * 16;
      int lb = pb ^ (((pb >> 7) & 7) << 4);
      gload_lds16(wbase + (size_t)(q0 + (lb >> 7)) * 1024 + k0 + ((lb & 127) >> 2),
                  (char*)Bi[buf] + pbase);
    }
  };

  f32x4 o_acc[4] = {};
  float m_run = -3.0e38f, l_run = 0.f;
  const float C2 = 0.045084439f;      // log2(e)/32
  const float PEN2 = 4.5084440e8f;    // 3.125e8 * log2(e)

  stage(0, 0);
  __syncthreads();
  int cur = 0;

  for (int kt = 0; kt < NT; ++kt) {
    const int k0 = kt * 32;
    if (kt + 1 < NT) stage(cur ^ 1, kt + 1);  // async prefetch, drained at barrier
    const bool diag = (kt >= NT - 2);

    // mask regs (L2-hot 4KB array)
    f32x4 mkv[2];
#pragma unroll
    for (int nt = 0; nt < 2; ++nt)
      mkv[nt] = *(const f32x4*)(mbase + k0 + nt * 16 + fq * 4);

    // S^T = K·Q^T : s_acc[nt][j] = S[k = k0+nt*16+fq*4+j][q = qrow]
    f32x4 s_acc[2] = {};
    __builtin_amdgcn_s_setprio(1);
#pragma unroll
    for (int kk = 0; kk < 2; ++kk)
#pragma unroll
      for (int nt = 0; nt < 2; ++nt) {
        int r = nt * 16 + fr;
        int cb = fq * 16 + kk * 64;
        bf16x8 kf = *(const bf16x8*)((const char*)Ks[cur] + (((r << 7) + cb) ^ ((r & 7) << 4)));
        s_acc[nt] = MFMA16(kf, kk == 0 ? qf0 : qf1, s_acc[nt]);
      }
    __builtin_amdgcn_s_setprio(0);

    // bias from LDS: bias[q = wid*16+fr][k = nt*16+fq*4+{0..3}]
    f32x4 bv[2];
#pragma unroll
    for (int nt = 0; nt < 2; ++nt) {
      int lbyte = (wid * 16 + fr) * 128 + nt * 64 + fq * 16;
      bv[nt] = *(const f32x4*)((const char*)Bi[cur] + (lbyte ^ ((fr & 7) << 4)));
    }

    // logits in log2 domain
    float p[8];
#pragma unroll
    for (int nt = 0; nt < 2; ++nt)
#pragma unroll
      for (int j = 0; j < 4; ++j) {
        float s = (s_acc[nt][j] + bv[nt][j]) * C2 - (1.0f - mkv[nt][j]) * PEN2;
        if (diag && (k0 + nt * 16 + fq * 4 + j) > qrow) s = -3.0e38f;
        p[nt * 4 + j] = s;
      }

    // tree max over 8 + 2 shuffles -> row max
    float t4[4];
#pragma unroll
    for (int i = 0; i < 4; ++i) t4[i] = fmaxf(p[i], p[i + 4]);
    float pmax = fmaxf(fmaxf(t4[0], t4[1]), fmaxf(t4[2], t4[3]));
    pmax = fmaxf(pmax, __shfl_xor(pmax, 16));
    pmax = fmaxf(pmax, __shfl_xor(pmax, 32));

    // defer-max: rescale only when max grew past THR (11.5 log2 ~ 8 nats)
    if (!__all(pmax - m_run <= 11.5f)) {
      float mnew = fmaxf(m_run, pmax);
      float corr = fast_exp2(m_run - mnew);
      m_run = mnew;
      l_run *= corr;
#pragma unroll
      for (int nt = 0; nt < 4; ++nt) o_acc[nt] *= corr;
    }

#pragma unroll
    for (int i = 0; i < 8; ++i) p[i] = fast_exp2(p[i] - m_run);
    float a4[4];
#pragma unroll
    for (int i = 0; i < 4; ++i) a4[i] = p[i] + p[i + 4];
    float rsum = (a4[0] + a4[1]) + (a4[2] + a4[3]);
    rsum += __shfl_xor(rsum, 16);
    rsum += __shfl_xor(rsum, 32);
    l_run += rsum;

    // P[q=fr][k] -> per-wave LDS (cvt_pk, b64 write)
    {
      uint2 w2;
      w2.x = cvt_pk_bf16(p[0], p[1]);
      w2.y = cvt_pk_bf16(p[2], p[3]);
      *(uint2*)&Ps[wid][fr * 40 + fq * 4] = w2;
      w2.x = cvt_pk_bf16(p[4], p[5]);
      w2.y = cvt_pk_bf16(p[6], p[7]);
      *(uint2*)&Ps[wid][fr * 40 + 16 + fq * 4] = w2;
    }
    asm volatile("s_waitcnt lgkmcnt(0)" ::: "memory");
    bf16x8 pf = *(const bf16x8*)&Ps[wid][fr * 40 + fq * 8];  // A[q][k 4x8]

    // O += V^T · P : o_acc[nt][j] = O[q = qrow][d = nt*16+fq*4+j]
    __builtin_amdgcn_s_setprio(1);
#pragma unroll
    for (int nt = 0; nt < 4; ++nt) {
      int r = nt * 16 + fr;
      int byte = (r << 6) + (fq * 16 ^ (((r >> 1) & 3) << 4));
      bf16x8 vf = *(const bf16x8*)((const char*)Vs[cur] + byte);
      o_acc[nt] = MFMA16(vf, pf, o_acc[nt]);
    }
    __builtin_amdgcn_s_setprio(0);

    __syncthreads();  // all waves done with [cur]; prefetch drained
    cur ^= 1;
  }

  // normalize + write merged-head bf16 [4096][1024]
  float rl = 1.0f / l_run;
  size_t row = (size_t)(b * 1024 + q0 + wid * 16 + fr);
#pragma unroll
  for (int nt = 0; nt < 4; ++nt) {
    uint2 sv;
    sv.x = cvt_pk_bf16(o_acc[nt][0] * rl, o_acc[nt][1] * rl);
    sv.y = cvt_pk_bf16(o_acc[nt][2] * rl, o_acc[nt][3] * rl);
    int col = (h & 15) * 64 + nt * 16 + fq * 4;
    *(uint2*)&Aout[row * 1024 + col] = sv;
  }
}

// ---------------------------------------------------------------------------
extern "C" void kernel_launch(void* const* d_in, const int* in_sizes, int n_in,
                              void* d_out, int out_size, void* d_ws, size_t ws_size,
                              hipStream_t stream) {
  const float* query = (const float*)d_in[0];
  const float* key   = (const float*)d_in[1];
  const float* value = (const float*)d_in[2];
  const float* mask  = (const float*)d_in[3];
  const float* wts   = (const float*)d_in[4];
  const float* Wq    = (const float*)d_in[5];
  const float* bq    = (const float*)d_in[6];
  const float* Wk    = (const float*)d_in[7];
  const float* bk    = (const float*)d_in[8];
  const float* Wv    = (const float*)d_in[9];
  const float* bv    = (const float*)d_in[10];
  const float* Wo    = (const float*)d_in[11];
  const float* bo    = (const float*)d_in[12];

  char* ws = (char*)d_ws;
  const size_t MB = 1u << 20;
  short* qbf = (short*)(ws + 0);        // 8 MB  (reused as attn out)
  short* kbf = (short*)(ws + 8 * MB);   // 8 MB
  short* vbf = (short*)(ws + 16 * MB);  // 8 MB
  short* Wqb = (short*)(ws + 24 * MB);  // 2 MB
  short* Wkb = (short*)(ws + 26 * MB);
  short* Wvb = (short*)(ws + 28 * MB);
  short* Wob = (short*)(ws + 30 * MB);
  short* Qh  = (short*)(ws + 32 * MB);  // 8 MB [B,N,T,DH]
  short* Kh  = (short*)(ws + 40 * MB);  // 8 MB [B,N,T,DH]
  short* Vth = (short*)(ws + 48 * MB);  // 8 MB [B,N,DH,T]
  short* attnb = qbf;                   // alias: qbf dead after proj_qkv

  cvt_all<<<dim3(2048), dim3(256), 0, stream>>>(query, key, value, Wq, Wk, Wv, Wo,
                                                qbf, kbf, vbf, Wqb, Wkb, Wvb, Wob);
  proj_qkv<<<dim3(32, 8, 3), dim3(256), 0, stream>>>(qbf, kbf, vbf, Wqb, Wkb, Wvb,
                                                     bq, bk, bv, Qh, Kh, Vth);
  attn_kernel<<<dim3(16, 64), dim3(256), 0, stream>>>(Qh, Kh, Vth, wts, mask, attnb);
  gemm_out<<<dim3(32, 8), dim3(256), 0, stream>>>(attnb, Wob, bo, (float*)d_out);
}

// Round 14
// 135.503 us; speedup vs baseline: 1.1724x; 1.0496x over previous
//
#include <hip/hip_runtime.h>
#include <cstddef>

// ---------------------------------------------------------------------------
// MultiHead attention, B=4 T=1024 D=1024 N=16 DH=64, SCALE=32, causal + bias.
// Round 14: attn tail rebuilt — mask as bf16 penalties in LDS (staged once;
// no per-tile global loads polluting vmcnt), split-barrier counted-vmcnt
// pipeline: tile t+1 staged at end of iter t-1, waited (vmcnt(4), never 0
// mid-loop) at end of iter t => one FULL iteration of slack. 4 blocks/CU.
// GEMMs = R10/R13 (128x128 dbuf). cvt unchanged.
// ---------------------------------------------------------------------------

typedef __attribute__((ext_vector_type(8))) short bf16x8;
typedef __attribute__((ext_vector_type(4))) float f32x4;

#define MFMA16(a, b, c) __builtin_amdgcn_mfma_f32_16x16x32_bf16(a, b, c, 0, 0, 0)

__device__ __forceinline__ short f2bf(float f) {
  union { float f; unsigned int i; } v; v.f = f;
  unsigned int r = v.i + 0x7FFFu + ((v.i >> 16) & 1u);  // RNE
  return (short)(r >> 16);
}

__device__ __forceinline__ float fast_exp2(float x) {
  float r;
  asm volatile("v_exp_f32 %0, %1" : "=v"(r) : "v"(x));
  return r;
}

__device__ __forceinline__ unsigned int cvt_pk_bf16(float lo, float hi) {
  unsigned int r;
  asm volatile("v_cvt_pk_bf16_f32 %0, %1, %2" : "=v"(r) : "v"(lo), "v"(hi));
  return r;
}

__device__ __forceinline__ void gload_lds16(const void* g, void* l) {
  __builtin_amdgcn_global_load_lds(
      (const __attribute__((address_space(1))) void*)g,
      (__attribute__((address_space(3))) void*)l, 16, 0, 0);
}

// ---------------------------------------------------------------------------
// Fused f32 -> bf16 conversion for all 7 tensors (one launch).
// ---------------------------------------------------------------------------
__global__ __launch_bounds__(256) void cvt_all(
    const float* __restrict__ q, const float* __restrict__ k, const float* __restrict__ v,
    const float* __restrict__ wq, const float* __restrict__ wk,
    const float* __restrict__ wv, const float* __restrict__ wo,
    short* __restrict__ qb, short* __restrict__ kb, short* __restrict__ vb,
    short* __restrict__ wqb, short* __restrict__ wkb,
    short* __restrict__ wvb, short* __restrict__ wob) {
  const int total = 16 * 1048576 / 4;  // vec4 count
  int stride = gridDim.x * blockDim.x;
  for (int i = blockIdx.x * blockDim.x + threadIdx.x; i < total; i += stride) {
    int e = i * 4;
    int chunk = e >> 20;
    const float* s;
    short* d;
    int off;
    if (chunk < 12) {
      if (chunk < 4)      { s = q; d = qb; }
      else if (chunk < 8) { s = k; d = kb; }
      else                { s = v; d = vb; }
      off = e & (4 * 1048576 - 1);
    } else {
      int w = chunk - 12;
      if (w == 0)      { s = wq; d = wqb; }
      else if (w == 1) { s = wk; d = wkb; }
      else if (w == 2) { s = wv; d = wvb; }
      else             { s = wo; d = wob; }
      off = e & (1048576 - 1);
    }
    float4 x = *(const float4*)(s + off);
    short4 o;
    o.x = f2bf(x.x); o.y = f2bf(x.y); o.z = f2bf(x.z); o.w = f2bf(x.w);
    *(short4*)(d + off) = o;
  }
}

// ---------------------------------------------------------------------------
// Fused Q/K/V projection: 128x128 tile, 4 waves (2x2), BK=64, double-buffered
// 64KB LDS, one barrier per K-step (R10, measured best).
// ---------------------------------------------------------------------------
__global__ __launch_bounds__(256) void proj_qkv(
    const short* __restrict__ qA, const short* __restrict__ kA, const short* __restrict__ vA,
    const short* __restrict__ Wqb, const short* __restrict__ Wkb, const short* __restrict__ Wvb,
    const float* __restrict__ bq, const float* __restrict__ bk, const float* __restrict__ bv,
    short* __restrict__ Qh, short* __restrict__ Kh, short* __restrict__ Vth) {
  __shared__ short DS[2][16384];  // per buf: As 8192 + Bs 8192 shorts = 32KB

  const int m0 = blockIdx.x * 128;
  const int n0 = blockIdx.y * 128;
  const int z = blockIdx.z;

  const short *A, *W;
  const float* bias;
  if (z == 0)      { A = qA; W = Wqb; bias = bq; }
  else if (z == 1) { A = kA; W = Wkb; bias = bk; }
  else             { A = vA; W = Wvb; bias = bv; }

  const int tid = threadIdx.x;
  const int wid = tid >> 6, lane = tid & 63;
  const int wr = wid >> 1, wc = wid & 1;
  const int fr = lane & 15, fq = lane >> 4;

  auto stage = [&](int buf, int kt) {
#pragma unroll
    for (int c = 0; c < 4; ++c) {
      int pbase = c * 4096 + wid * 1024;
      int pb = pbase + lane * 16;
      int lb = pb ^ (((pb >> 7) & 7) << 4);
      int grow = lb >> 7, gcol = (lb & 127) >> 1;
      gload_lds16(A + (size_t)(m0 + grow) * 1024 + kt * 64 + gcol,
                  (char*)DS[buf] + pbase);
      gload_lds16(W + (size_t)(n0 + grow) * 1024 + kt * 64 + gcol,
                  (char*)(DS[buf] + 8192) + pbase);
    }
  };

  f32x4 acc[4][4] = {};
  stage(0, 0);
  __syncthreads();
  int cur = 0;

  for (int kt = 0; kt < 16; ++kt) {
    if (kt < 15) stage(cur ^ 1, kt + 1);  // prefetch, drained by end barrier
    const short* As = DS[cur];
    const short* Bs = DS[cur] + 8192;
#pragma unroll
    for (int kk = 0; kk < 2; ++kk) {
      bf16x8 af[4], bg[4];
      int cb = (fq * 8 + kk * 32) * 2;
#pragma unroll
      for (int m = 0; m < 4; ++m) {
        int r = wr * 64 + m * 16 + fr;
        af[m] = *(const bf16x8*)((const char*)As + (((r << 7) + cb) ^ ((r & 7) << 4)));
      }
#pragma unroll
      for (int n = 0; n < 4; ++n) {
        int r = wc * 64 + n * 16 + fr;
        bg[n] = *(const bf16x8*)((const char*)Bs + (((r << 7) + cb) ^ ((r & 7) << 4)));
      }
#pragma unroll
      for (int m = 0; m < 4; ++m)
#pragma unroll
        for (int n = 0; n < 4; ++n)
          acc[m][n] = MFMA16(af[m], bg[n], acc[m][n]);
    }
    __syncthreads();  // waves done with [cur]; prefetch into [cur^1] complete
    cur ^= 1;
  }

  if (z < 2) {
    short* dst = (z == 0) ? Qh : Kh;
#pragma unroll
    for (int m = 0; m < 4; ++m)
#pragma unroll
      for (int n = 0; n < 4; ++n) {
        int col = n0 + wc * 64 + n * 16 + fr;
        float bval = bias[col];
        int row0 = m0 + wr * 64 + m * 16 + fq * 4;
        int hh = col >> 6, dh = col & 63;
#pragma unroll
        for (int j = 0; j < 4; ++j) {
          int row = row0 + j;
          int bb = row >> 10, t = row & 1023;
          dst[(((size_t)(bb * 16 + hh)) * 1024 + t) * 64 + dh] = f2bf(acc[m][n][j] + bval);
        }
      }
  } else {
    // transpose 128x128 block through LDS, then coalesced bf16x8 stores
    short* Vt = (short*)DS;  // [128 cols][136] shorts = 34.8 KB
#pragma unroll
    for (int m = 0; m < 4; ++m)
#pragma unroll
      for (int n = 0; n < 4; ++n) {
        int coll = wc * 64 + n * 16 + fr;
        float bval = bias[n0 + coll];
        int rowl0 = wr * 64 + m * 16 + fq * 4;
#pragma unroll
        for (int j = 0; j < 4; ++j)
          Vt[coll * 136 + rowl0 + j] = f2bf(acc[m][n][j] + bval);
      }
    __syncthreads();
    const int bb = m0 >> 10, t0 = m0 & 1023;
#pragma unroll
    for (int it = 0; it < 8; ++it) {
      int qq = tid + it * 256;          // 2048 chunks: 128 rows x 16 chunks
      int rowl = qq >> 4, seg = qq & 15;
      bf16x8 vv = *(const bf16x8*)&Vt[rowl * 136 + seg * 8];
      int cg = n0 + rowl, hh = cg >> 6, dh = cg & 63;
      *(bf16x8*)&Vth[(((size_t)(bb * 16 + hh)) * 64 + dh) * 1024 + t0 + seg * 8] = vv;
    }
  }
}

// ---------------------------------------------------------------------------
// Output projection: 128x128 tile, 4 waves (2x2), dbuf, one barrier per kt
// (R10, measured best). d_out f32 = A @ Wo^T + bo.
// ---------------------------------------------------------------------------
__global__ __launch_bounds__(256) void gemm_out(const short* __restrict__ A,
                                                const short* __restrict__ W,
                                                const float* __restrict__ bias,
                                                float* __restrict__ C) {
  __shared__ short DS[2][16384];

  const int m0 = blockIdx.x * 128;
  const int n0 = blockIdx.y * 128;

  const int tid = threadIdx.x;
  const int wid = tid >> 6, lane = tid & 63;
  const int wr = wid >> 1, wc = wid & 1;
  const int fr = lane & 15, fq = lane >> 4;

  auto stage = [&](int buf, int kt) {
#pragma unroll
    for (int c = 0; c < 4; ++c) {
      int pbase = c * 4096 + wid * 1024;
      int pb = pbase + lane * 16;
      int lb = pb ^ (((pb >> 7) & 7) << 4);
      int grow = lb >> 7, gcol = (lb & 127) >> 1;
      gload_lds16(A + (size_t)(m0 + grow) * 1024 + kt * 64 + gcol,
                  (char*)DS[buf] + pbase);
      gload_lds16(W + (size_t)(n0 + grow) * 1024 + kt * 64 + gcol,
                  (char*)(DS[buf] + 8192) + pbase);
    }
  };

  f32x4 acc[4][4] = {};
  stage(0, 0);
  __syncthreads();
  int cur = 0;

  for (int kt = 0; kt < 16; ++kt) {
    if (kt < 15) stage(cur ^ 1, kt + 1);
    const short* As = DS[cur];
    const short* Bs = DS[cur] + 8192;
#pragma unroll
    for (int kk = 0; kk < 2; ++kk) {
      bf16x8 af[4], bg[4];
      int cb = (fq * 8 + kk * 32) * 2;
#pragma unroll
      for (int m = 0; m < 4; ++m) {
        int r = wr * 64 + m * 16 + fr;
        af[m] = *(const bf16x8*)((const char*)As + (((r << 7) + cb) ^ ((r & 7) << 4)));
      }
#pragma unroll
      for (int n = 0; n < 4; ++n) {
        int r = wc * 64 + n * 16 + fr;
        bg[n] = *(const bf16x8*)((const char*)Bs + (((r << 7) + cb) ^ ((r & 7) << 4)));
      }
#pragma unroll
      for (int m = 0; m < 4; ++m)
#pragma unroll
        for (int n = 0; n < 4; ++n)
          acc[m][n] = MFMA16(af[m], bg[n], acc[m][n]);
    }
    __syncthreads();
    cur ^= 1;
  }

#pragma unroll
  for (int m = 0; m < 4; ++m)
#pragma unroll
    for (int n = 0; n < 4; ++n) {
      int col = n0 + wc * 64 + n * 16 + fr;
      float bval = bias[col];
      int row0 = m0 + wr * 64 + m * 16 + fq * 4;
#pragma unroll
      for (int j = 0; j < 4; ++j)
        C[(size_t)(row0 + j) * 1024 + col] = acc[m][n][j] + bval;
    }
}

// ---------------------------------------------------------------------------
// Flash attention: grid (16 q-tiles, 64 heads), 4 waves, QBLK=64, KVBLK=32.
// LDS 39KB -> 4 blocks/CU. Mask staged ONCE as bf16 penalties (no per-tile
// global loads => vmcnt carries ONLY the 4 stage loads/tile). Split-barrier
// counted-vmcnt tail: stage(t+2) after barrier-1, vmcnt(4) (never 0 mid-loop)
// + barrier-2 => tile t+1 has one full iteration of latency slack.
// ---------------------------------------------------------------------------
__global__ __launch_bounds__(256) void attn_kernel(
    const short* __restrict__ Qh, const short* __restrict__ Kh,
    const short* __restrict__ Vth, const float* __restrict__ Wb,
    const float* __restrict__ mask, short* __restrict__ Aout) {
  __shared__ short Ks[2][2048];        // [k 0..31][dh 0..63] bf16, 128B rows, ^((r&7)<<4)
  __shared__ short Vs[2][2048];        // [dh 0..63][k 0..31] bf16, 64B rows, ^(((r>>1)&3)<<4)
  __shared__ float Bi[2][2048];        // [q 0..63][k 0..31] f32, 128B rows, ^((r&7)<<4)
  __shared__ unsigned short Mp[1024];  // bf16 mask penalties (staged once)
  __shared__ short Ps[4][16 * 40];     // per-wave P [16 q][32 k], stride 40

  const int tid = threadIdx.x;
  const int wid = tid >> 6, lane = tid & 63;
  const int fr = lane & 15, fq = lane >> 4;
  const int h = blockIdx.y, b = h >> 4;
  const int qi = (int)gridDim.x - 1 - (int)blockIdx.x;  // heavy tiles first
  const int q0 = qi * 64;
  const int qrow = q0 + wid * 16 + fr;   // this lane's q-row
  const int NT = 2 * qi + 2;             // 32-wide KV tiles (NT >= 2)

  const float C2 = 0.045084439f;      // log2(e)/32
  const float PEN2 = 4.5084440e8f;    // 3.125e8 * log2(e)

  const short* qbase = Qh + ((size_t)h * 1024 + qrow) * 64 + fq * 8;
  bf16x8 qf0 = *(const bf16x8*)qbase;
  bf16x8 qf1 = *(const bf16x8*)(qbase + 32);

  const short* Kbase = Kh + (size_t)h * 1024 * 64;
  const short* Vbase = Vth + (size_t)h * 64 * 1024;
  const float* wbase = Wb + (size_t)h * 1024 * 1024;

  auto stage = [&](int buf, int kt2) {  // 4 gload_lds16 per wave per tile
    const int k0 = kt2 * 32;
    {  // K tile 4KB: rows k, 128B
      int pb = wid * 1024 + lane * 16;
      int lb = pb ^ (((pb >> 7) & 7) << 4);
      gload_lds16(Kbase + (size_t)(k0 + (lb >> 7)) * 64 + ((lb & 127) >> 1),
                  (char*)Ks[buf] + wid * 1024);
    }
    {  // V^T tile 4KB: rows dh, 64B, swizzle on (row>>1)&3
      int pb = wid * 1024 + lane * 16;
      int lb = pb ^ (((pb >> 7) & 3) << 4);
      gload_lds16(Vbase + (size_t)(lb >> 6) * 1024 + k0 + ((lb & 63) >> 1),
                  (char*)Vs[buf] + wid * 1024);
    }
#pragma unroll
    for (int c = 0; c < 2; ++c) {  // bias tile 8KB: rows q, 128B (32 f32)
      int pbase = c * 4096 + wid * 1024;
      int pb = pbase + lane * 16;
      int lb = pb ^ (((pb >> 7) & 7) << 4);
      gload_lds16(wbase + (size_t)(q0 + (lb >> 7)) * 1024 + k0 + ((lb & 127) >> 2),
                  (char*)Bi[buf] + pbase);
    }
  };

  // prologue: mask penalties -> LDS (bf16), first two tiles staged
  {
    float4 mv = *(const float4*)(mask + b * 1024 + tid * 4);
    ushort4 mp;
    mp.x = (unsigned short)f2bf((1.0f - mv.x) * PEN2);
    mp.y = (unsigned short)f2bf((1.0f - mv.y) * PEN2);
    mp.z = (unsigned short)f2bf((1.0f - mv.z) * PEN2);
    mp.w = (unsigned short)f2bf((1.0f - mv.w) * PEN2);
    *(ushort4*)&Mp[tid * 4] = mp;
  }
  stage(0, 0);
  stage(1, 1);
  asm volatile("s_waitcnt vmcnt(4) lgkmcnt(0)" ::: "memory");  // t0 + mask ready
  __builtin_amdgcn_sched_barrier(0);
  __builtin_amdgcn_s_barrier();
  __builtin_amdgcn_sched_barrier(0);

  f32x4 o_acc[4] = {};
  float m_run = -3.0e38f, l_run = 0.f;
  int cur = 0;

  for (int kt = 0; kt < NT; ++kt) {
    const int k0 = kt * 32;
    const bool diag = (kt >= NT - 2);

    // S^T = K·Q^T : s_acc[nt][j] = S[k = k0+nt*16+fq*4+j][q = qrow]
    f32x4 s_acc[2] = {};
    __builtin_amdgcn_s_setprio(1);
#pragma unroll
    for (int kk = 0; kk < 2; ++kk)
#pragma unroll
      for (int nt = 0; nt < 2; ++nt) {
        int r = nt * 16 + fr;
        int cb = fq * 16 + kk * 64;
        bf16x8 kf = *(const bf16x8*)((const char*)Ks[cur] + (((r << 7) + cb) ^ ((r & 7) << 4)));
        s_acc[nt] = MFMA16(kf, kk == 0 ? qf0 : qf1, s_acc[nt]);
      }
    __builtin_amdgcn_s_setprio(0);

    // bias from LDS: bias[q = wid*16+fr][k = nt*16+fq*4+{0..3}]
    f32x4 bv[2];
#pragma unroll
    for (int nt = 0; nt < 2; ++nt) {
      int lbyte = (wid * 16 + fr) * 128 + nt * 64 + fq * 16;
      bv[nt] = *(const f32x4*)((const char*)Bi[cur] + (lbyte ^ ((fr & 7) << 4)));
    }
    // mask penalties from LDS (bf16 -> f32; same-address broadcast, free)
    float pen[8];
#pragma unroll
    for (int nt = 0; nt < 2; ++nt) {
      ushort4 m4 = *(const ushort4*)&Mp[k0 + nt * 16 + fq * 4];
      pen[nt * 4 + 0] = __uint_as_float((unsigned)m4.x << 16);
      pen[nt * 4 + 1] = __uint_as_float((unsigned)m4.y << 16);
      pen[nt * 4 + 2] = __uint_as_float((unsigned)m4.z << 16);
      pen[nt * 4 + 3] = __uint_as_float((unsigned)m4.w << 16);
    }

    // logits in log2 domain
    float p[8];
#pragma unroll
    for (int nt = 0; nt < 2; ++nt)
#pragma unroll
      for (int j = 0; j < 4; ++j) {
        float s = (s_acc[nt][j] + bv[nt][j]) * C2 - pen[nt * 4 + j];
        if (diag && (k0 + nt * 16 + fq * 4 + j) > qrow) s = -3.0e38f;
        p[nt * 4 + j] = s;
      }

    // tree max over 8 + 2 shuffles -> row max
    float t4[4];
#pragma unroll
    for (int i = 0; i < 4; ++i) t4[i] = fmaxf(p[i], p[i + 4]);
    float pmax = fmaxf(fmaxf(t4[0], t4[1]), fmaxf(t4[2], t4[3]));
    pmax = fmaxf(pmax, __shfl_xor(pmax, 16));
    pmax = fmaxf(pmax, __shfl_xor(pmax, 32));

    // defer-max: rescale only when max grew past THR (11.5 log2 ~ 8 nats)
    if (!__all(pmax - m_run <= 11.5f)) {
      float mnew = fmaxf(m_run, pmax);
      float corr = fast_exp2(m_run - mnew);
      m_run = mnew;
      l_run *= corr;
#pragma unroll
      for (int nt = 0; nt < 4; ++nt) o_acc[nt] *= corr;
    }

#pragma unroll
    for (int i = 0; i < 8; ++i) p[i] = fast_exp2(p[i] - m_run);
    float a4[4];
#pragma unroll
    for (int i = 0; i < 4; ++i) a4[i] = p[i] + p[i + 4];
    float rsum = (a4[0] + a4[1]) + (a4[2] + a4[3]);
    rsum += __shfl_xor(rsum, 16);
    rsum += __shfl_xor(rsum, 32);
    l_run += rsum;

    // P[q=fr][k] -> per-wave LDS (cvt_pk, b64 write)
    {
      uint2 w2;
      w2.x = cvt_pk_bf16(p[0], p[1]);
      w2.y = cvt_pk_bf16(p[2], p[3]);
      *(uint2*)&Ps[wid][fr * 40 + fq * 4] = w2;
      w2.x = cvt_pk_bf16(p[4], p[5]);
      w2.y = cvt_pk_bf16(p[6], p[7]);
      *(uint2*)&Ps[wid][fr * 40 + 16 + fq * 4] = w2;
    }
    asm volatile("s_waitcnt lgkmcnt(0)" ::: "memory");
    __builtin_amdgcn_sched_barrier(0);
    bf16x8 pf = *(const bf16x8*)&Ps[wid][fr * 40 + fq * 8];  // A[q][k 4x8]

    // O += V^T · P : o_acc[nt][j] = O[q = qrow][d = nt*16+fq*4+j]
    __builtin_amdgcn_s_setprio(1);
#pragma unroll
    for (int nt = 0; nt < 4; ++nt) {
      int r = nt * 16 + fr;
      int byte = (r << 6) + (fq * 16 ^ (((r >> 1) & 3) << 4));
      bf16x8 vf = *(const bf16x8*)((const char*)Vs[cur] + byte);
      o_acc[nt] = MFMA16(vf, pf, o_acc[nt]);
    }
    __builtin_amdgcn_s_setprio(0);

    // -------- split-barrier counted-vmcnt tail --------
    if (kt + 2 < NT) {
      __builtin_amdgcn_sched_barrier(0);
      __builtin_amdgcn_s_barrier();       // (1) all waves done reading buf[cur]
      __builtin_amdgcn_sched_barrier(0);
      stage(cur, kt + 2);                 // overwrite just-freed buffer
    }
    if (kt + 1 < NT) {
      if (kt + 2 < NT) asm volatile("s_waitcnt vmcnt(4)" ::: "memory");
      else             asm volatile("s_waitcnt vmcnt(0)" ::: "memory");
      __builtin_amdgcn_sched_barrier(0);
      __builtin_amdgcn_s_barrier();       // (2) tile kt+1 landed for ALL waves
      __builtin_amdgcn_sched_barrier(0);
    }
    cur ^= 1;
  }

  // normalize + write merged-head bf16 [4096][1024]
  float rl = 1.0f / l_run;
  size_t row = (size_t)(b * 1024 + q0 + wid * 16 + fr);
#pragma unroll
  for (int nt = 0; nt < 4; ++nt) {
    uint2 sv;
    sv.x = cvt_pk_bf16(o_acc[nt][0] * rl, o_acc[nt][1] * rl);
    sv.y = cvt_pk_bf16(o_acc[nt][2] * rl, o_acc[nt][3] * rl);
    int col = (h & 15) * 64 + nt * 16 + fq * 4;
    *(uint2*)&Aout[row * 1024 + col] = sv;
  }
}

// ---------------------------------------------------------------------------
extern "C" void kernel_launch(void* const* d_in, const int* in_sizes, int n_in,
                              void* d_out, int out_size, void* d_ws, size_t ws_size,
                              hipStream_t stream) {
  const float* query = (const float*)d_in[0];
  const float* key   = (const float*)d_in[1];
  const float* value = (const float*)d_in[2];
  const float* mask  = (const float*)d_in[3];
  const float* wts   = (const float*)d_in[4];
  const float* Wq    = (const float*)d_in[5];
  const float* bq    = (const float*)d_in[6];
  const float* Wk    = (const float*)d_in[7];
  const float* bk    = (const float*)d_in[8];
  const float* Wv    = (const float*)d_in[9];
  const float* bv    = (const float*)d_in[10];
  const float* Wo    = (const float*)d_in[11];
  const float* bo    = (const float*)d_in[12];

  char* ws = (char*)d_ws;
  const size_t MB = 1u << 20;
  short* qbf = (short*)(ws + 0);        // 8 MB  (reused as attn out)
  short* kbf = (short*)(ws + 8 * MB);   // 8 MB
  short* vbf = (short*)(ws + 16 * MB);  // 8 MB
  short* Wqb = (short*)(ws + 24 * MB);  // 2 MB
  short* Wkb = (short*)(ws + 26 * MB);
  short* Wvb = (short*)(ws + 28 * MB);
  short* Wob = (short*)(ws + 30 * MB);
  short* Qh  = (short*)(ws + 32 * MB);  // 8 MB [B,N,T,DH]
  short* Kh  = (short*)(ws + 40 * MB);  // 8 MB [B,N,T,DH]
  short* Vth = (short*)(ws + 48 * MB);  // 8 MB [B,N,DH,T]
  short* attnb = qbf;                   // alias: qbf dead after proj_qkv

  cvt_all<<<dim3(2048), dim3(256), 0, stream>>>(query, key, value, Wq, Wk, Wv, Wo,
                                                qbf, kbf, vbf, Wqb, Wkb, Wvb, Wob);
  proj_qkv<<<dim3(32, 8, 3), dim3(256), 0, stream>>>(qbf, kbf, vbf, Wqb, Wkb, Wvb,
                                                     bq, bk, bv, Qh, Kh, Vth);
  attn_kernel<<<dim3(16, 64), dim3(256), 0, stream>>>(Qh, Kh, Vth, wts, mask, attnb);
  gemm_out<<<dim3(32, 8), dim3(256), 0, stream>>>(attnb, Wob, bo, (float*)d_out);
}

// Round 15
// 126.956 us; speedup vs baseline: 1.2513x; 1.0673x over previous
//
#include <hip/hip_runtime.h>
#include <cstddef>

// ---------------------------------------------------------------------------
// MultiHead attention, B=4 T=1024 D=1024 N=16 DH=64, SCALE=32, causal + bias.
// Round 15: attn LOAD-BALANCED — block bx handles q-tile pair (15-bx, bx)
// sequentially => uniform 34 KV-tiles/block regardless of CU assignment
// (was: 1024 exactly-resident blocks with NT in [2..32]; worst CU ~128 tiles).
// Grid (8,64), 2 blocks/CU. R14 split-barrier counted-vmcnt loop unchanged.
// GEMMs = R10/R13 (128x128 dbuf). cvt unchanged.
// ---------------------------------------------------------------------------

typedef __attribute__((ext_vector_type(8))) short bf16x8;
typedef __attribute__((ext_vector_type(4))) float f32x4;

#define MFMA16(a, b, c) __builtin_amdgcn_mfma_f32_16x16x32_bf16(a, b, c, 0, 0, 0)

__device__ __forceinline__ short f2bf(float f) {
  union { float f; unsigned int i; } v; v.f = f;
  unsigned int r = v.i + 0x7FFFu + ((v.i >> 16) & 1u);  // RNE
  return (short)(r >> 16);
}

__device__ __forceinline__ float fast_exp2(float x) {
  float r;
  asm volatile("v_exp_f32 %0, %1" : "=v"(r) : "v"(x));
  return r;
}

__device__ __forceinline__ unsigned int cvt_pk_bf16(float lo, float hi) {
  unsigned int r;
  asm volatile("v_cvt_pk_bf16_f32 %0, %1, %2" : "=v"(r) : "v"(lo), "v"(hi));
  return r;
}

__device__ __forceinline__ void gload_lds16(const void* g, void* l) {
  __builtin_amdgcn_global_load_lds(
      (const __attribute__((address_space(1))) void*)g,
      (__attribute__((address_space(3))) void*)l, 16, 0, 0);
}

// ---------------------------------------------------------------------------
// Fused f32 -> bf16 conversion for all 7 tensors (one launch).
// ---------------------------------------------------------------------------
__global__ __launch_bounds__(256) void cvt_all(
    const float* __restrict__ q, const float* __restrict__ k, const float* __restrict__ v,
    const float* __restrict__ wq, const float* __restrict__ wk,
    const float* __restrict__ wv, const float* __restrict__ wo,
    short* __restrict__ qb, short* __restrict__ kb, short* __restrict__ vb,
    short* __restrict__ wqb, short* __restrict__ wkb,
    short* __restrict__ wvb, short* __restrict__ wob) {
  const int total = 16 * 1048576 / 4;  // vec4 count
  int stride = gridDim.x * blockDim.x;
  for (int i = blockIdx.x * blockDim.x + threadIdx.x; i < total; i += stride) {
    int e = i * 4;
    int chunk = e >> 20;
    const float* s;
    short* d;
    int off;
    if (chunk < 12) {
      if (chunk < 4)      { s = q; d = qb; }
      else if (chunk < 8) { s = k; d = kb; }
      else                { s = v; d = vb; }
      off = e & (4 * 1048576 - 1);
    } else {
      int w = chunk - 12;
      if (w == 0)      { s = wq; d = wqb; }
      else if (w == 1) { s = wk; d = wkb; }
      else if (w == 2) { s = wv; d = wvb; }
      else             { s = wo; d = wob; }
      off = e & (1048576 - 1);
    }
    float4 x = *(const float4*)(s + off);
    short4 o;
    o.x = f2bf(x.x); o.y = f2bf(x.y); o.z = f2bf(x.z); o.w = f2bf(x.w);
    *(short4*)(d + off) = o;
  }
}

// ---------------------------------------------------------------------------
// Fused Q/K/V projection: 128x128 tile, 4 waves (2x2), BK=64, double-buffered
// 64KB LDS, one barrier per K-step (R10, measured best).
// ---------------------------------------------------------------------------
__global__ __launch_bounds__(256) void proj_qkv(
    const short* __restrict__ qA, const short* __restrict__ kA, const short* __restrict__ vA,
    const short* __restrict__ Wqb, const short* __restrict__ Wkb, const short* __restrict__ Wvb,
    const float* __restrict__ bq, const float* __restrict__ bk, const float* __restrict__ bv,
    short* __restrict__ Qh, short* __restrict__ Kh, short* __restrict__ Vth) {
  __shared__ short DS[2][16384];  // per buf: As 8192 + Bs 8192 shorts = 32KB

  const int m0 = blockIdx.x * 128;
  const int n0 = blockIdx.y * 128;
  const int z = blockIdx.z;

  const short *A, *W;
  const float* bias;
  if (z == 0)      { A = qA; W = Wqb; bias = bq; }
  else if (z == 1) { A = kA; W = Wkb; bias = bk; }
  else             { A = vA; W = Wvb; bias = bv; }

  const int tid = threadIdx.x;
  const int wid = tid >> 6, lane = tid & 63;
  const int wr = wid >> 1, wc = wid & 1;
  const int fr = lane & 15, fq = lane >> 4;

  auto stage = [&](int buf, int kt) {
#pragma unroll
    for (int c = 0; c < 4; ++c) {
      int pbase = c * 4096 + wid * 1024;
      int pb = pbase + lane * 16;
      int lb = pb ^ (((pb >> 7) & 7) << 4);
      int grow = lb >> 7, gcol = (lb & 127) >> 1;
      gload_lds16(A + (size_t)(m0 + grow) * 1024 + kt * 64 + gcol,
                  (char*)DS[buf] + pbase);
      gload_lds16(W + (size_t)(n0 + grow) * 1024 + kt * 64 + gcol,
                  (char*)(DS[buf] + 8192) + pbase);
    }
  };

  f32x4 acc[4][4] = {};
  stage(0, 0);
  __syncthreads();
  int cur = 0;

  for (int kt = 0; kt < 16; ++kt) {
    if (kt < 15) stage(cur ^ 1, kt + 1);  // prefetch, drained by end barrier
    const short* As = DS[cur];
    const short* Bs = DS[cur] + 8192;
#pragma unroll
    for (int kk = 0; kk < 2; ++kk) {
      bf16x8 af[4], bg[4];
      int cb = (fq * 8 + kk * 32) * 2;
#pragma unroll
      for (int m = 0; m < 4; ++m) {
        int r = wr * 64 + m * 16 + fr;
        af[m] = *(const bf16x8*)((const char*)As + (((r << 7) + cb) ^ ((r & 7) << 4)));
      }
#pragma unroll
      for (int n = 0; n < 4; ++n) {
        int r = wc * 64 + n * 16 + fr;
        bg[n] = *(const bf16x8*)((const char*)Bs + (((r << 7) + cb) ^ ((r & 7) << 4)));
      }
#pragma unroll
      for (int m = 0; m < 4; ++m)
#pragma unroll
        for (int n = 0; n < 4; ++n)
          acc[m][n] = MFMA16(af[m], bg[n], acc[m][n]);
    }
    __syncthreads();  // waves done with [cur]; prefetch into [cur^1] complete
    cur ^= 1;
  }

  if (z < 2) {
    short* dst = (z == 0) ? Qh : Kh;
#pragma unroll
    for (int m = 0; m < 4; ++m)
#pragma unroll
      for (int n = 0; n < 4; ++n) {
        int col = n0 + wc * 64 + n * 16 + fr;
        float bval = bias[col];
        int row0 = m0 + wr * 64 + m * 16 + fq * 4;
        int hh = col >> 6, dh = col & 63;
#pragma unroll
        for (int j = 0; j < 4; ++j) {
          int row = row0 + j;
          int bb = row >> 10, t = row & 1023;
          dst[(((size_t)(bb * 16 + hh)) * 1024 + t) * 64 + dh] = f2bf(acc[m][n][j] + bval);
        }
      }
  } else {
    // transpose 128x128 block through LDS, then coalesced bf16x8 stores
    short* Vt = (short*)DS;  // [128 cols][136] shorts = 34.8 KB
#pragma unroll
    for (int m = 0; m < 4; ++m)
#pragma unroll
      for (int n = 0; n < 4; ++n) {
        int coll = wc * 64 + n * 16 + fr;
        float bval = bias[n0 + coll];
        int rowl0 = wr * 64 + m * 16 + fq * 4;
#pragma unroll
        for (int j = 0; j < 4; ++j)
          Vt[coll * 136 + rowl0 + j] = f2bf(acc[m][n][j] + bval);
      }
    __syncthreads();
    const int bb = m0 >> 10, t0 = m0 & 1023;
#pragma unroll
    for (int it = 0; it < 8; ++it) {
      int qq = tid + it * 256;          // 2048 chunks: 128 rows x 16 chunks
      int rowl = qq >> 4, seg = qq & 15;
      bf16x8 vv = *(const bf16x8*)&Vt[rowl * 136 + seg * 8];
      int cg = n0 + rowl, hh = cg >> 6, dh = cg & 63;
      *(bf16x8*)&Vth[(((size_t)(bb * 16 + hh)) * 64 + dh) * 1024 + t0 + seg * 8] = vv;
    }
  }
}

// ---------------------------------------------------------------------------
// Output projection: 128x128 tile, 4 waves (2x2), dbuf, one barrier per kt
// (R10, measured best). d_out f32 = A @ Wo^T + bo.
// ---------------------------------------------------------------------------
__global__ __launch_bounds__(256) void gemm_out(const short* __restrict__ A,
                                                const short* __restrict__ W,
                                                const float* __restrict__ bias,
                                                float* __restrict__ C) {
  __shared__ short DS[2][16384];

  const int m0 = blockIdx.x * 128;
  const int n0 = blockIdx.y * 128;

  const int tid = threadIdx.x;
  const int wid = tid >> 6, lane = tid & 63;
  const int wr = wid >> 1, wc = wid & 1;
  const int fr = lane & 15, fq = lane >> 4;

  auto stage = [&](int buf, int kt) {
#pragma unroll
    for (int c = 0; c < 4; ++c) {
      int pbase = c * 4096 + wid * 1024;
      int pb = pbase + lane * 16;
      int lb = pb ^ (((pb >> 7) & 7) << 4);
      int grow = lb >> 7, gcol = (lb & 127) >> 1;
      gload_lds16(A + (size_t)(m0 + grow) * 1024 + kt * 64 + gcol,
                  (char*)DS[buf] + pbase);
      gload_lds16(W + (size_t)(n0 + grow) * 1024 + kt * 64 + gcol,
                  (char*)(DS[buf] + 8192) + pbase);
    }
  };

  f32x4 acc[4][4] = {};
  stage(0, 0);
  __syncthreads();
  int cur = 0;

  for (int kt = 0; kt < 16; ++kt) {
    if (kt < 15) stage(cur ^ 1, kt + 1);
    const short* As = DS[cur];
    const short* Bs = DS[cur] + 8192;
#pragma unroll
    for (int kk = 0; kk < 2; ++kk) {
      bf16x8 af[4], bg[4];
      int cb = (fq * 8 + kk * 32) * 2;
#pragma unroll
      for (int m = 0; m < 4; ++m) {
        int r = wr * 64 + m * 16 + fr;
        af[m] = *(const bf16x8*)((const char*)As + (((r << 7) + cb) ^ ((r & 7) << 4)));
      }
#pragma unroll
      for (int n = 0; n < 4; ++n) {
        int r = wc * 64 + n * 16 + fr;
        bg[n] = *(const bf16x8*)((const char*)Bs + (((r << 7) + cb) ^ ((r & 7) << 4)));
      }
#pragma unroll
      for (int m = 0; m < 4; ++m)
#pragma unroll
        for (int n = 0; n < 4; ++n)
          acc[m][n] = MFMA16(af[m], bg[n], acc[m][n]);
    }
    __syncthreads();
    cur ^= 1;
  }

#pragma unroll
  for (int m = 0; m < 4; ++m)
#pragma unroll
    for (int n = 0; n < 4; ++n) {
      int col = n0 + wc * 64 + n * 16 + fr;
      float bval = bias[col];
      int row0 = m0 + wr * 64 + m * 16 + fq * 4;
#pragma unroll
      for (int j = 0; j < 4; ++j)
        C[(size_t)(row0 + j) * 1024 + col] = acc[m][n][j] + bval;
    }
}

// ---------------------------------------------------------------------------
// Flash attention: grid (8 q-pairs, 64 heads), 4 waves, QBLK=64, KVBLK=32.
// Block bx processes q-tiles {15-bx, bx} sequentially => uniform 34 tiles.
// R14 loop: mask as bf16 penalties in LDS (staged once), split-barrier
// counted-vmcnt pipeline (vmcnt(4), never 0 mid-loop).
// ---------------------------------------------------------------------------
__global__ __launch_bounds__(256) void attn_kernel(
    const short* __restrict__ Qh, const short* __restrict__ Kh,
    const short* __restrict__ Vth, const float* __restrict__ Wb,
    const float* __restrict__ mask, short* __restrict__ Aout) {
  __shared__ short Ks[2][2048];        // [k 0..31][dh 0..63] bf16, 128B rows, ^((r&7)<<4)
  __shared__ short Vs[2][2048];        // [dh 0..63][k 0..31] bf16, 64B rows, ^(((r>>1)&3)<<4)
  __shared__ float Bi[2][2048];        // [q 0..63][k 0..31] f32, 128B rows, ^((r&7)<<4)
  __shared__ unsigned short Mp[1024];  // bf16 mask penalties (staged once)
  __shared__ short Ps[4][16 * 40];     // per-wave P [16 q][32 k], stride 40

  const int tid = threadIdx.x;
  const int wid = tid >> 6, lane = tid & 63;
  const int fr = lane & 15, fq = lane >> 4;
  const int h = blockIdx.y, b = h >> 4;
  const int bx = blockIdx.x;

  const float C2 = 0.045084439f;      // log2(e)/32
  const float PEN2 = 4.5084440e8f;    // 3.125e8 * log2(e)

  const short* Kbase = Kh + (size_t)h * 1024 * 64;
  const short* Vbase = Vth + (size_t)h * 64 * 1024;
  const float* wbase = Wb + (size_t)h * 1024 * 1024;

  auto stage = [&](int buf, int kt2, int q0) {  // 4 gload_lds16 per wave
    const int k0 = kt2 * 32;
    {  // K tile 4KB: rows k, 128B
      int pb = wid * 1024 + lane * 16;
      int lb = pb ^ (((pb >> 7) & 7) << 4);
      gload_lds16(Kbase + (size_t)(k0 + (lb >> 7)) * 64 + ((lb & 127) >> 1),
                  (char*)Ks[buf] + wid * 1024);
    }
    {  // V^T tile 4KB: rows dh, 64B, swizzle on (row>>1)&3
      int pb = wid * 1024 + lane * 16;
      int lb = pb ^ (((pb >> 7) & 3) << 4);
      gload_lds16(Vbase + (size_t)(lb >> 6) * 1024 + k0 + ((lb & 63) >> 1),
                  (char*)Vs[buf] + wid * 1024);
    }
#pragma unroll
    for (int c = 0; c < 2; ++c) {  // bias tile 8KB: rows q, 128B (32 f32)
      int pbase = c * 4096 + wid * 1024;
      int pb = pbase + lane * 16;
      int lb = pb ^ (((pb >> 7) & 7) << 4);
      gload_lds16(wbase + (size_t)(q0 + (lb >> 7)) * 1024 + k0 + ((lb & 127) >> 2),
                  (char*)Bi[buf] + pbase);
    }
  };

  // mask penalties -> LDS (bf16), once per block
  {
    float4 mv = *(const float4*)(mask + b * 1024 + tid * 4);
    ushort4 mp;
    mp.x = (unsigned short)f2bf((1.0f - mv.x) * PEN2);
    mp.y = (unsigned short)f2bf((1.0f - mv.y) * PEN2);
    mp.z = (unsigned short)f2bf((1.0f - mv.z) * PEN2);
    mp.w = (unsigned short)f2bf((1.0f - mv.w) * PEN2);
    *(ushort4*)&Mp[tid * 4] = mp;
  }

  for (int half = 0; half < 2; ++half) {
    const int qi = half ? bx : 15 - bx;
    const int q0 = qi * 64;
    const int qrow = q0 + wid * 16 + fr;   // this lane's q-row
    const int NT = 2 * qi + 2;             // 32-wide KV tiles (NT >= 2)

    const short* qbase = Qh + ((size_t)h * 1024 + qrow) * 64 + fq * 8;
    bf16x8 qf0 = *(const bf16x8*)qbase;
    bf16x8 qf1 = *(const bf16x8*)(qbase + 32);

    if (half) {
      // all waves must be done reading buffers from previous half
      __builtin_amdgcn_sched_barrier(0);
      __builtin_amdgcn_s_barrier();
      __builtin_amdgcn_sched_barrier(0);
    }
    stage(0, 0, q0);
    stage(1, 1, q0);
    asm volatile("s_waitcnt vmcnt(4) lgkmcnt(0)" ::: "memory");  // tile0 (+mask) ready
    __builtin_amdgcn_sched_barrier(0);
    __builtin_amdgcn_s_barrier();
    __builtin_amdgcn_sched_barrier(0);

    f32x4 o_acc[4] = {};
    float m_run = -3.0e38f, l_run = 0.f;
    int cur = 0;

    for (int kt = 0; kt < NT; ++kt) {
      const int k0 = kt * 32;
      const bool diag = (kt >= NT - 2);

      // S^T = K·Q^T : s_acc[nt][j] = S[k = k0+nt*16+fq*4+j][q = qrow]
      f32x4 s_acc[2] = {};
      __builtin_amdgcn_s_setprio(1);
#pragma unroll
      for (int kk = 0; kk < 2; ++kk)
#pragma unroll
        for (int nt = 0; nt < 2; ++nt) {
          int r = nt * 16 + fr;
          int cb = fq * 16 + kk * 64;
          bf16x8 kf = *(const bf16x8*)((const char*)Ks[cur] + (((r << 7) + cb) ^ ((r & 7) << 4)));
          s_acc[nt] = MFMA16(kf, kk == 0 ? qf0 : qf1, s_acc[nt]);
        }
      __builtin_amdgcn_s_setprio(0);

      // bias from LDS: bias[q = wid*16+fr][k = nt*16+fq*4+{0..3}]
      f32x4 bv[2];
#pragma unroll
      for (int nt = 0; nt < 2; ++nt) {
        int lbyte = (wid * 16 + fr) * 128 + nt * 64 + fq * 16;
        bv[nt] = *(const f32x4*)((const char*)Bi[cur] + (lbyte ^ ((fr & 7) << 4)));
      }
      // mask penalties from LDS (bf16 -> f32)
      float pen[8];
#pragma unroll
      for (int nt = 0; nt < 2; ++nt) {
        ushort4 m4 = *(const ushort4*)&Mp[k0 + nt * 16 + fq * 4];
        pen[nt * 4 + 0] = __uint_as_float((unsigned)m4.x << 16);
        pen[nt * 4 + 1] = __uint_as_float((unsigned)m4.y << 16);
        pen[nt * 4 + 2] = __uint_as_float((unsigned)m4.z << 16);
        pen[nt * 4 + 3] = __uint_as_float((unsigned)m4.w << 16);
      }

      // logits in log2 domain
      float p[8];
#pragma unroll
      for (int nt = 0; nt < 2; ++nt)
#pragma unroll
        for (int j = 0; j < 4; ++j) {
          float s = (s_acc[nt][j] + bv[nt][j]) * C2 - pen[nt * 4 + j];
          if (diag && (k0 + nt * 16 + fq * 4 + j) > qrow) s = -3.0e38f;
          p[nt * 4 + j] = s;
        }

      // tree max over 8 + 2 shuffles -> row max
      float t4[4];
#pragma unroll
      for (int i = 0; i < 4; ++i) t4[i] = fmaxf(p[i], p[i + 4]);
      float pmax = fmaxf(fmaxf(t4[0], t4[1]), fmaxf(t4[2], t4[3]));
      pmax = fmaxf(pmax, __shfl_xor(pmax, 16));
      pmax = fmaxf(pmax, __shfl_xor(pmax, 32));

      // defer-max: rescale only when max grew past THR (11.5 log2 ~ 8 nats)
      if (!__all(pmax - m_run <= 11.5f)) {
        float mnew = fmaxf(m_run, pmax);
        float corr = fast_exp2(m_run - mnew);
        m_run = mnew;
        l_run *= corr;
#pragma unroll
        for (int nt = 0; nt < 4; ++nt) o_acc[nt] *= corr;
      }

#pragma unroll
      for (int i = 0; i < 8; ++i) p[i] = fast_exp2(p[i] - m_run);
      float a4[4];
#pragma unroll
      for (int i = 0; i < 4; ++i) a4[i] = p[i] + p[i + 4];
      float rsum = (a4[0] + a4[1]) + (a4[2] + a4[3]);
      rsum += __shfl_xor(rsum, 16);
      rsum += __shfl_xor(rsum, 32);
      l_run += rsum;

      // P[q=fr][k] -> per-wave LDS (cvt_pk, b64 write)
      {
        uint2 w2;
        w2.x = cvt_pk_bf16(p[0], p[1]);
        w2.y = cvt_pk_bf16(p[2], p[3]);
        *(uint2*)&Ps[wid][fr * 40 + fq * 4] = w2;
        w2.x = cvt_pk_bf16(p[4], p[5]);
        w2.y = cvt_pk_bf16(p[6], p[7]);
        *(uint2*)&Ps[wid][fr * 40 + 16 + fq * 4] = w2;
      }
      asm volatile("s_waitcnt lgkmcnt(0)" ::: "memory");
      __builtin_amdgcn_sched_barrier(0);
      bf16x8 pf = *(const bf16x8*)&Ps[wid][fr * 40 + fq * 8];  // A[q][k 4x8]

      // O += V^T · P : o_acc[nt][j] = O[q = qrow][d = nt*16+fq*4+j]
      __builtin_amdgcn_s_setprio(1);
#pragma unroll
      for (int nt = 0; nt < 4; ++nt) {
        int r = nt * 16 + fr;
        int byte = (r << 6) + (fq * 16 ^ (((r >> 1) & 3) << 4));
        bf16x8 vf = *(const bf16x8*)((const char*)Vs[cur] + byte);
        o_acc[nt] = MFMA16(vf, pf, o_acc[nt]);
      }
      __builtin_amdgcn_s_setprio(0);

      // -------- split-barrier counted-vmcnt tail --------
      if (kt + 2 < NT) {
        __builtin_amdgcn_sched_barrier(0);
        __builtin_amdgcn_s_barrier();       // (1) all waves done reading buf[cur]
        __builtin_amdgcn_sched_barrier(0);
        stage(cur, kt + 2, q0);             // overwrite just-freed buffer
      }
      if (kt + 1 < NT) {
        if (kt + 2 < NT) asm volatile("s_waitcnt vmcnt(4)" ::: "memory");
        else             asm volatile("s_waitcnt vmcnt(0)" ::: "memory");
        __builtin_amdgcn_sched_barrier(0);
        __builtin_amdgcn_s_barrier();       // (2) tile kt+1 landed for ALL waves
        __builtin_amdgcn_sched_barrier(0);
      }
      cur ^= 1;
    }

    // normalize + write merged-head bf16 [4096][1024] for this half
    float rl = 1.0f / l_run;
    size_t row = (size_t)(b * 1024 + q0 + wid * 16 + fr);
#pragma unroll
    for (int nt = 0; nt < 4; ++nt) {
      uint2 sv;
      sv.x = cvt_pk_bf16(o_acc[nt][0] * rl, o_acc[nt][1] * rl);
      sv.y = cvt_pk_bf16(o_acc[nt][2] * rl, o_acc[nt][3] * rl);
      int col = (h & 15) * 64 + nt * 16 + fq * 4;
      *(uint2*)&Aout[row * 1024 + col] = sv;
    }
  }
}

// ---------------------------------------------------------------------------
extern "C" void kernel_launch(void* const* d_in, const int* in_sizes, int n_in,
                              void* d_out, int out_size, void* d_ws, size_t ws_size,
                              hipStream_t stream) {
  const float* query = (const float*)d_in[0];
  const float* key   = (const float*)d_in[1];
  const float* value = (const float*)d_in[2];
  const float* mask  = (const float*)d_in[3];
  const float* wts   = (const float*)d_in[4];
  const float* Wq    = (const float*)d_in[5];
  const float* bq    = (const float*)d_in[6];
  const float* Wk    = (const float*)d_in[7];
  const float* bk    = (const float*)d_in[8];
  const float* Wv    = (const float*)d_in[9];
  const float* bv    = (const float*)d_in[10];
  const float* Wo    = (const float*)d_in[11];
  const float* bo    = (const float*)d_in[12];

  char* ws = (char*)d_ws;
  const size_t MB = 1u << 20;
  short* qbf = (short*)(ws + 0);        // 8 MB  (reused as attn out)
  short* kbf = (short*)(ws + 8 * MB);   // 8 MB
  short* vbf = (short*)(ws + 16 * MB);  // 8 MB
  short* Wqb = (short*)(ws + 24 * MB);  // 2 MB
  short* Wkb = (short*)(ws + 26 * MB);
  short* Wvb = (short*)(ws + 28 * MB);
  short* Wob = (short*)(ws + 30 * MB);
  short* Qh  = (short*)(ws + 32 * MB);  // 8 MB [B,N,T,DH]
  short* Kh  = (short*)(ws + 40 * MB);  // 8 MB [B,N,T,DH]
  short* Vth = (short*)(ws + 48 * MB);  // 8 MB [B,N,DH,T]
  short* attnb = qbf;                   // alias: qbf dead after proj_qkv

  cvt_all<<<dim3(2048), dim3(256), 0, stream>>>(query, key, value, Wq, Wk, Wv, Wo,
                                                qbf, kbf, vbf, Wqb, Wkb, Wvb, Wob);
  proj_qkv<<<dim3(32, 8, 3), dim3(256), 0, stream>>>(qbf, kbf, vbf, Wqb, Wkb, Wvb,
                                                     bq, bk, bv, Qh, Kh, Vth);
  attn_kernel<<<dim3(8, 64), dim3(256), 0, stream>>>(Qh, Kh, Vth, wts, mask, attnb);
  gemm_out<<<dim3(32, 8), dim3(256), 0, stream>>>(attnb, Wob, bo, (float*)d_out);
}

// Round 16
// 119.005 us; speedup vs baseline: 1.3349x; 1.0668x over previous
//
#include <hip/hip_runtime.h>
#include <cstddef>

// ---------------------------------------------------------------------------
// MultiHead attention, B=4 T=1024 D=1024 N=16 DH=64, SCALE=32, causal + bias.
// Round 16: attn KVBLK 32->64 inside the R15 balanced-pair structure: halves
// barrier/vmcnt count (34->17 tiles/block) at same VALU/MFMA totals. LDS 75KB
// (2 blocks/CU — exactly what the 512-block grid supplies). vmcnt(8) steady.
// GEMMs = R10/R13 (128x128 dbuf). cvt unchanged.
// ---------------------------------------------------------------------------

typedef __attribute__((ext_vector_type(8))) short bf16x8;
typedef __attribute__((ext_vector_type(4))) float f32x4;

#define MFMA16(a, b, c) __builtin_amdgcn_mfma_f32_16x16x32_bf16(a, b, c, 0, 0, 0)

__device__ __forceinline__ short f2bf(float f) {
  union { float f; unsigned int i; } v; v.f = f;
  unsigned int r = v.i + 0x7FFFu + ((v.i >> 16) & 1u);  // RNE
  return (short)(r >> 16);
}

__device__ __forceinline__ float fast_exp2(float x) {
  float r;
  asm volatile("v_exp_f32 %0, %1" : "=v"(r) : "v"(x));
  return r;
}

__device__ __forceinline__ unsigned int cvt_pk_bf16(float lo, float hi) {
  unsigned int r;
  asm volatile("v_cvt_pk_bf16_f32 %0, %1, %2" : "=v"(r) : "v"(lo), "v"(hi));
  return r;
}

__device__ __forceinline__ void gload_lds16(const void* g, void* l) {
  __builtin_amdgcn_global_load_lds(
      (const __attribute__((address_space(1))) void*)g,
      (__attribute__((address_space(3))) void*)l, 16, 0, 0);
}

// ---------------------------------------------------------------------------
// Fused f32 -> bf16 conversion for all 7 tensors (one launch).
// ---------------------------------------------------------------------------
__global__ __launch_bounds__(256) void cvt_all(
    const float* __restrict__ q, const float* __restrict__ k, const float* __restrict__ v,
    const float* __restrict__ wq, const float* __restrict__ wk,
    const float* __restrict__ wv, const float* __restrict__ wo,
    short* __restrict__ qb, short* __restrict__ kb, short* __restrict__ vb,
    short* __restrict__ wqb, short* __restrict__ wkb,
    short* __restrict__ wvb, short* __restrict__ wob) {
  const int total = 16 * 1048576 / 4;  // vec4 count
  int stride = gridDim.x * blockDim.x;
  for (int i = blockIdx.x * blockDim.x + threadIdx.x; i < total; i += stride) {
    int e = i * 4;
    int chunk = e >> 20;
    const float* s;
    short* d;
    int off;
    if (chunk < 12) {
      if (chunk < 4)      { s = q; d = qb; }
      else if (chunk < 8) { s = k; d = kb; }
      else                { s = v; d = vb; }
      off = e & (4 * 1048576 - 1);
    } else {
      int w = chunk - 12;
      if (w == 0)      { s = wq; d = wqb; }
      else if (w == 1) { s = wk; d = wkb; }
      else if (w == 2) { s = wv; d = wvb; }
      else             { s = wo; d = wob; }
      off = e & (1048576 - 1);
    }
    float4 x = *(const float4*)(s + off);
    short4 o;
    o.x = f2bf(x.x); o.y = f2bf(x.y); o.z = f2bf(x.z); o.w = f2bf(x.w);
    *(short4*)(d + off) = o;
  }
}

// ---------------------------------------------------------------------------
// Fused Q/K/V projection: 128x128 tile, 4 waves (2x2), BK=64, double-buffered
// 64KB LDS, one barrier per K-step (R10, measured best).
// ---------------------------------------------------------------------------
__global__ __launch_bounds__(256) void proj_qkv(
    const short* __restrict__ qA, const short* __restrict__ kA, const short* __restrict__ vA,
    const short* __restrict__ Wqb, const short* __restrict__ Wkb, const short* __restrict__ Wvb,
    const float* __restrict__ bq, const float* __restrict__ bk, const float* __restrict__ bv,
    short* __restrict__ Qh, short* __restrict__ Kh, short* __restrict__ Vth) {
  __shared__ short DS[2][16384];  // per buf: As 8192 + Bs 8192 shorts = 32KB

  const int m0 = blockIdx.x * 128;
  const int n0 = blockIdx.y * 128;
  const int z = blockIdx.z;

  const short *A, *W;
  const float* bias;
  if (z == 0)      { A = qA; W = Wqb; bias = bq; }
  else if (z == 1) { A = kA; W = Wkb; bias = bk; }
  else             { A = vA; W = Wvb; bias = bv; }

  const int tid = threadIdx.x;
  const int wid = tid >> 6, lane = tid & 63;
  const int wr = wid >> 1, wc = wid & 1;
  const int fr = lane & 15, fq = lane >> 4;

  auto stage = [&](int buf, int kt) {
#pragma unroll
    for (int c = 0; c < 4; ++c) {
      int pbase = c * 4096 + wid * 1024;
      int pb = pbase + lane * 16;
      int lb = pb ^ (((pb >> 7) & 7) << 4);
      int grow = lb >> 7, gcol = (lb & 127) >> 1;
      gload_lds16(A + (size_t)(m0 + grow) * 1024 + kt * 64 + gcol,
                  (char*)DS[buf] + pbase);
      gload_lds16(W + (size_t)(n0 + grow) * 1024 + kt * 64 + gcol,
                  (char*)(DS[buf] + 8192) + pbase);
    }
  };

  f32x4 acc[4][4] = {};
  stage(0, 0);
  __syncthreads();
  int cur = 0;

  for (int kt = 0; kt < 16; ++kt) {
    if (kt < 15) stage(cur ^ 1, kt + 1);  // prefetch, drained by end barrier
    const short* As = DS[cur];
    const short* Bs = DS[cur] + 8192;
#pragma unroll
    for (int kk = 0; kk < 2; ++kk) {
      bf16x8 af[4], bg[4];
      int cb = (fq * 8 + kk * 32) * 2;
#pragma unroll
      for (int m = 0; m < 4; ++m) {
        int r = wr * 64 + m * 16 + fr;
        af[m] = *(const bf16x8*)((const char*)As + (((r << 7) + cb) ^ ((r & 7) << 4)));
      }
#pragma unroll
      for (int n = 0; n < 4; ++n) {
        int r = wc * 64 + n * 16 + fr;
        bg[n] = *(const bf16x8*)((const char*)Bs + (((r << 7) + cb) ^ ((r & 7) << 4)));
      }
#pragma unroll
      for (int m = 0; m < 4; ++m)
#pragma unroll
        for (int n = 0; n < 4; ++n)
          acc[m][n] = MFMA16(af[m], bg[n], acc[m][n]);
    }
    __syncthreads();  // waves done with [cur]; prefetch into [cur^1] complete
    cur ^= 1;
  }

  if (z < 2) {
    short* dst = (z == 0) ? Qh : Kh;
#pragma unroll
    for (int m = 0; m < 4; ++m)
#pragma unroll
      for (int n = 0; n < 4; ++n) {
        int col = n0 + wc * 64 + n * 16 + fr;
        float bval = bias[col];
        int row0 = m0 + wr * 64 + m * 16 + fq * 4;
        int hh = col >> 6, dh = col & 63;
#pragma unroll
        for (int j = 0; j < 4; ++j) {
          int row = row0 + j;
          int bb = row >> 10, t = row & 1023;
          dst[(((size_t)(bb * 16 + hh)) * 1024 + t) * 64 + dh] = f2bf(acc[m][n][j] + bval);
        }
      }
  } else {
    // transpose 128x128 block through LDS, then coalesced bf16x8 stores
    short* Vt = (short*)DS;  // [128 cols][136] shorts = 34.8 KB
#pragma unroll
    for (int m = 0; m < 4; ++m)
#pragma unroll
      for (int n = 0; n < 4; ++n) {
        int coll = wc * 64 + n * 16 + fr;
        float bval = bias[n0 + coll];
        int rowl0 = wr * 64 + m * 16 + fq * 4;
#pragma unroll
        for (int j = 0; j < 4; ++j)
          Vt[coll * 136 + rowl0 + j] = f2bf(acc[m][n][j] + bval);
      }
    __syncthreads();
    const int bb = m0 >> 10, t0 = m0 & 1023;
#pragma unroll
    for (int it = 0; it < 8; ++it) {
      int qq = tid + it * 256;          // 2048 chunks: 128 rows x 16 chunks
      int rowl = qq >> 4, seg = qq & 15;
      bf16x8 vv = *(const bf16x8*)&Vt[rowl * 136 + seg * 8];
      int cg = n0 + rowl, hh = cg >> 6, dh = cg & 63;
      *(bf16x8*)&Vth[(((size_t)(bb * 16 + hh)) * 64 + dh) * 1024 + t0 + seg * 8] = vv;
    }
  }
}

// ---------------------------------------------------------------------------
// Output projection: 128x128 tile, 4 waves (2x2), dbuf, one barrier per kt
// (R10, measured best). d_out f32 = A @ Wo^T + bo.
// ---------------------------------------------------------------------------
__global__ __launch_bounds__(256) void gemm_out(const short* __restrict__ A,
                                                const short* __restrict__ W,
                                                const float* __restrict__ bias,
                                                float* __restrict__ C) {
  __shared__ short DS[2][16384];

  const int m0 = blockIdx.x * 128;
  const int n0 = blockIdx.y * 128;

  const int tid = threadIdx.x;
  const int wid = tid >> 6, lane = tid & 63;
  const int wr = wid >> 1, wc = wid & 1;
  const int fr = lane & 15, fq = lane >> 4;

  auto stage = [&](int buf, int kt) {
#pragma unroll
    for (int c = 0; c < 4; ++c) {
      int pbase = c * 4096 + wid * 1024;
      int pb = pbase + lane * 16;
      int lb = pb ^ (((pb >> 7) & 7) << 4);
      int grow = lb >> 7, gcol = (lb & 127) >> 1;
      gload_lds16(A + (size_t)(m0 + grow) * 1024 + kt * 64 + gcol,
                  (char*)DS[buf] + pbase);
      gload_lds16(W + (size_t)(n0 + grow) * 1024 + kt * 64 + gcol,
                  (char*)(DS[buf] + 8192) + pbase);
    }
  };

  f32x4 acc[4][4] = {};
  stage(0, 0);
  __syncthreads();
  int cur = 0;

  for (int kt = 0; kt < 16; ++kt) {
    if (kt < 15) stage(cur ^ 1, kt + 1);
    const short* As = DS[cur];
    const short* Bs = DS[cur] + 8192;
#pragma unroll
    for (int kk = 0; kk < 2; ++kk) {
      bf16x8 af[4], bg[4];
      int cb = (fq * 8 + kk * 32) * 2;
#pragma unroll
      for (int m = 0; m < 4; ++m) {
        int r = wr * 64 + m * 16 + fr;
        af[m] = *(const bf16x8*)((const char*)As + (((r << 7) + cb) ^ ((r & 7) << 4)));
      }
#pragma unroll
      for (int n = 0; n < 4; ++n) {
        int r = wc * 64 + n * 16 + fr;
        bg[n] = *(const bf16x8*)((const char*)Bs + (((r << 7) + cb) ^ ((r & 7) << 4)));
      }
#pragma unroll
      for (int m = 0; m < 4; ++m)
#pragma unroll
        for (int n = 0; n < 4; ++n)
          acc[m][n] = MFMA16(af[m], bg[n], acc[m][n]);
    }
    __syncthreads();
    cur ^= 1;
  }

#pragma unroll
  for (int m = 0; m < 4; ++m)
#pragma unroll
    for (int n = 0; n < 4; ++n) {
      int col = n0 + wc * 64 + n * 16 + fr;
      float bval = bias[col];
      int row0 = m0 + wr * 64 + m * 16 + fq * 4;
#pragma unroll
      for (int j = 0; j < 4; ++j)
        C[(size_t)(row0 + j) * 1024 + col] = acc[m][n][j] + bval;
    }
}

// ---------------------------------------------------------------------------
// Flash attention: grid (8 q-pairs, 64 heads), 4 waves, QBLK=64, KVBLK=64.
// Block bx processes q-tiles {15-bx, bx} sequentially => uniform 17 KV-tiles.
// Mask as bf16 penalties in LDS (staged once). Split-barrier counted-vmcnt
// pipeline: stage = 8 loads/tile; vmcnt(8) steady (never 0 mid-loop).
// ---------------------------------------------------------------------------
__global__ __launch_bounds__(256) void attn_kernel(
    const short* __restrict__ Qh, const short* __restrict__ Kh,
    const short* __restrict__ Vth, const float* __restrict__ Wb,
    const float* __restrict__ mask, short* __restrict__ Aout) {
  __shared__ short Ks[2][4096];        // [k 0..63][dh 0..63] bf16, 128B rows, ^((r&7)<<4)
  __shared__ short Vs[2][4096];        // [dh 0..63][k 0..63] bf16, 128B rows, ^((r&7)<<4)
  __shared__ float Bi[2][4096];        // [q 0..63][k 0..63] f32, 256B rows, ^(((pb>>8)&7)<<4)
  __shared__ unsigned short Mp[1024];  // bf16 mask penalties (staged once)
  __shared__ short Ps[4][16 * 72];     // per-wave P [16 q][64 k], stride 72

  const int tid = threadIdx.x;
  const int wid = tid >> 6, lane = tid & 63;
  const int fr = lane & 15, fq = lane >> 4;
  const int h = blockIdx.y, b = h >> 4;
  const int bx = blockIdx.x;

  const float C2 = 0.045084439f;      // log2(e)/32
  const float PEN2 = 4.5084440e8f;    // 3.125e8 * log2(e)

  const short* Kbase = Kh + (size_t)h * 1024 * 64;
  const short* Vbase = Vth + (size_t)h * 64 * 1024;
  const float* wbase = Wb + (size_t)h * 1024 * 1024;

  auto stage = [&](int buf, int kt2, int q0) {  // 8 gload_lds16 per wave
    const int k0 = kt2 * 64;
#pragma unroll
    for (int c = 0; c < 2; ++c) {  // K tile 8KB + V^T tile 8KB (128B rows)
      int pbase = c * 4096 + wid * 1024;
      int pb = pbase + lane * 16;
      int lb = pb ^ (((pb >> 7) & 7) << 4);
      int grow = lb >> 7, gcol = (lb & 127) >> 1;
      gload_lds16(Kbase + (size_t)(k0 + grow) * 64 + gcol, (char*)Ks[buf] + pbase);
      gload_lds16(Vbase + (size_t)grow * 1024 + k0 + gcol, (char*)Vs[buf] + pbase);
    }
#pragma unroll
    for (int c = 0; c < 4; ++c) {  // bias tile 16KB: rows q, 256B (64 f32)
      int pbase = c * 4096 + wid * 1024;
      int pb = pbase + lane * 16;
      int lb = pb ^ (((pb >> 8) & 7) << 4);
      int grow = lb >> 8, gcolf = (lb & 255) >> 2;
      gload_lds16(wbase + (size_t)(q0 + grow) * 1024 + k0 + gcolf,
                  (char*)Bi[buf] + pbase);
    }
  };

  // mask penalties -> LDS (bf16), once per block
  {
    float4 mv = *(const float4*)(mask + b * 1024 + tid * 4);
    ushort4 mp;
    mp.x = (unsigned short)f2bf((1.0f - mv.x) * PEN2);
    mp.y = (unsigned short)f2bf((1.0f - mv.y) * PEN2);
    mp.z = (unsigned short)f2bf((1.0f - mv.z) * PEN2);
    mp.w = (unsigned short)f2bf((1.0f - mv.w) * PEN2);
    *(ushort4*)&Mp[tid * 4] = mp;
  }

  for (int half = 0; half < 2; ++half) {
    const int qi = half ? bx : 15 - bx;
    const int q0 = qi * 64;
    const int qrow = q0 + wid * 16 + fr;   // this lane's q-row
    const int NT = qi + 1;                 // 64-wide KV tiles (NT >= 1)

    const short* qbase = Qh + ((size_t)h * 1024 + qrow) * 64 + fq * 8;
    bf16x8 qf0 = *(const bf16x8*)qbase;
    bf16x8 qf1 = *(const bf16x8*)(qbase + 32);

    if (half) {
      // all waves must be done reading buffers from previous half
      __builtin_amdgcn_sched_barrier(0);
      __builtin_amdgcn_s_barrier();
      __builtin_amdgcn_sched_barrier(0);
    }
    stage(0, 0, q0);
    if (NT > 1) stage(1, 1, q0);
    // wait tile0 (+ mask ds_write on first half); tile1's 8 loads may fly
    if (NT > 1) asm volatile("s_waitcnt vmcnt(8) lgkmcnt(0)" ::: "memory");
    else        asm volatile("s_waitcnt vmcnt(0) lgkmcnt(0)" ::: "memory");
    __builtin_amdgcn_sched_barrier(0);
    __builtin_amdgcn_s_barrier();
    __builtin_amdgcn_sched_barrier(0);

    f32x4 o_acc[4] = {};
    float m_run = -3.0e38f, l_run = 0.f;
    int cur = 0;

    for (int kt = 0; kt < NT; ++kt) {
      const int k0 = kt * 64;
      const bool diag = (kt == NT - 1);

      // S^T = K·Q^T : s_acc[nt][j] = S[k = k0+nt*16+fq*4+j][q = qrow]
      f32x4 s_acc[4] = {};
      __builtin_amdgcn_s_setprio(1);
#pragma unroll
      for (int kk = 0; kk < 2; ++kk)
#pragma unroll
        for (int nt = 0; nt < 4; ++nt) {
          int r = nt * 16 + fr;
          int cb = fq * 16 + kk * 64;
          bf16x8 kf = *(const bf16x8*)((const char*)Ks[cur] + (((r << 7) + cb) ^ ((r & 7) << 4)));
          s_acc[nt] = MFMA16(kf, kk == 0 ? qf0 : qf1, s_acc[nt]);
        }
      __builtin_amdgcn_s_setprio(0);

      // bias from LDS: bias[q = wid*16+fr][k = nt*16+fq*4+{0..3}]
      f32x4 bv[4];
#pragma unroll
      for (int nt = 0; nt < 4; ++nt) {
        int lbyte = (wid * 16 + fr) * 256 + nt * 64 + fq * 16;
        bv[nt] = *(const f32x4*)((const char*)Bi[cur] + (lbyte ^ ((fr & 7) << 4)));
      }
      // mask penalties from LDS (bf16 -> f32)
      float pen[16];
#pragma unroll
      for (int nt = 0; nt < 4; ++nt) {
        ushort4 m4 = *(const ushort4*)&Mp[k0 + nt * 16 + fq * 4];
        pen[nt * 4 + 0] = __uint_as_float((unsigned)m4.x << 16);
        pen[nt * 4 + 1] = __uint_as_float((unsigned)m4.y << 16);
        pen[nt * 4 + 2] = __uint_as_float((unsigned)m4.z << 16);
        pen[nt * 4 + 3] = __uint_as_float((unsigned)m4.w << 16);
      }

      // logits in log2 domain
      float p[16];
#pragma unroll
      for (int nt = 0; nt < 4; ++nt)
#pragma unroll
        for (int j = 0; j < 4; ++j) {
          float s = (s_acc[nt][j] + bv[nt][j]) * C2 - pen[nt * 4 + j];
          if (diag && (nt * 16 + fq * 4 + j) > (wid * 16 + fr)) s = -3.0e38f;
          p[nt * 4 + j] = s;
        }

      // tree max over 16 + 2 shuffles -> row max
      float t8[8], t4m[4];
#pragma unroll
      for (int i = 0; i < 8; ++i) t8[i] = fmaxf(p[i], p[i + 8]);
#pragma unroll
      for (int i = 0; i < 4; ++i) t4m[i] = fmaxf(t8[i], t8[i + 4]);
      float pmax = fmaxf(fmaxf(t4m[0], t4m[1]), fmaxf(t4m[2], t4m[3]));
      pmax = fmaxf(pmax, __shfl_xor(pmax, 16));
      pmax = fmaxf(pmax, __shfl_xor(pmax, 32));

      // defer-max: rescale only when max grew past THR (11.5 log2 ~ 8 nats)
      if (!__all(pmax - m_run <= 11.5f)) {
        float mnew = fmaxf(m_run, pmax);
        float corr = fast_exp2(m_run - mnew);
        m_run = mnew;
        l_run *= corr;
#pragma unroll
        for (int nt = 0; nt < 4; ++nt) o_acc[nt] *= corr;
      }

#pragma unroll
      for (int i = 0; i < 16; ++i) p[i] = fast_exp2(p[i] - m_run);
      float a8[8], a4[4];
#pragma unroll
      for (int i = 0; i < 8; ++i) a8[i] = p[i] + p[i + 8];
#pragma unroll
      for (int i = 0; i < 4; ++i) a4[i] = a8[i] + a8[i + 4];
      float rsum = (a4[0] + a4[1]) + (a4[2] + a4[3]);
      rsum += __shfl_xor(rsum, 16);
      rsum += __shfl_xor(rsum, 32);
      l_run += rsum;

      // P[q=fr][k] -> per-wave LDS (cvt_pk, b64 writes)
#pragma unroll
      for (int nt = 0; nt < 4; ++nt) {
        uint2 w2;
        w2.x = cvt_pk_bf16(p[nt * 4 + 0], p[nt * 4 + 1]);
        w2.y = cvt_pk_bf16(p[nt * 4 + 2], p[nt * 4 + 3]);
        *(uint2*)&Ps[wid][fr * 72 + nt * 16 + fq * 4] = w2;
      }
      asm volatile("s_waitcnt lgkmcnt(0)" ::: "memory");
      __builtin_amdgcn_sched_barrier(0);
      bf16x8 pf0 = *(const bf16x8*)&Ps[wid][fr * 72 + fq * 8];
      bf16x8 pf1 = *(const bf16x8*)&Ps[wid][fr * 72 + fq * 8 + 32];

      // O += V^T · P : o_acc[nt][j] = O[q = qrow][d = nt*16+fq*4+j]
      __builtin_amdgcn_s_setprio(1);
#pragma unroll
      for (int kk = 0; kk < 2; ++kk)
#pragma unroll
        for (int nt = 0; nt < 4; ++nt) {
          int r = nt * 16 + fr;
          int cb = fq * 16 + kk * 64;
          bf16x8 vf = *(const bf16x8*)((const char*)Vs[cur] + (((r << 7) + cb) ^ ((r & 7) << 4)));
          o_acc[nt] = MFMA16(vf, kk == 0 ? pf0 : pf1, o_acc[nt]);
        }
      __builtin_amdgcn_s_setprio(0);

      // -------- split-barrier counted-vmcnt tail --------
      if (kt + 2 < NT) {
        __builtin_amdgcn_sched_barrier(0);
        __builtin_amdgcn_s_barrier();       // (1) all waves done reading buf[cur]
        __builtin_amdgcn_sched_barrier(0);
        stage(cur, kt + 2, q0);             // overwrite just-freed buffer
      }
      if (kt + 1 < NT) {
        if (kt + 2 < NT) asm volatile("s_waitcnt vmcnt(8)" ::: "memory");
        else             asm volatile("s_waitcnt vmcnt(0)" ::: "memory");
        __builtin_amdgcn_sched_barrier(0);
        __builtin_amdgcn_s_barrier();       // (2) tile kt+1 landed for ALL waves
        __builtin_amdgcn_sched_barrier(0);
      }
      cur ^= 1;
    }

    // normalize + write merged-head bf16 [4096][1024] for this half
    float rl = 1.0f / l_run;
    size_t row = (size_t)(b * 1024 + q0 + wid * 16 + fr);
#pragma unroll
    for (int nt = 0; nt < 4; ++nt) {
      uint2 sv;
      sv.x = cvt_pk_bf16(o_acc[nt][0] * rl, o_acc[nt][1] * rl);
      sv.y = cvt_pk_bf16(o_acc[nt][2] * rl, o_acc[nt][3] * rl);
      int col = (h & 15) * 64 + nt * 16 + fq * 4;
      *(uint2*)&Aout[row * 1024 + col] = sv;
    }
  }
}

// ---------------------------------------------------------------------------
extern "C" void kernel_launch(void* const* d_in, const int* in_sizes, int n_in,
                              void* d_out, int out_size, void* d_ws, size_t ws_size,
                              hipStream_t stream) {
  const float* query = (const float*)d_in[0];
  const float* key   = (const float*)d_in[1];
  const float* value = (const float*)d_in[2];
  const float* mask  = (const float*)d_in[3];
  const float* wts   = (const float*)d_in[4];
  const float* Wq    = (const float*)d_in[5];
  const float* bq    = (const float*)d_in[6];
  const float* Wk    = (const float*)d_in[7];
  const float* bk    = (const float*)d_in[8];
  const float* Wv    = (const float*)d_in[9];
  const float* bv    = (const float*)d_in[10];
  const float* Wo    = (const float*)d_in[11];
  const float* bo    = (const float*)d_in[12];

  char* ws = (char*)d_ws;
  const size_t MB = 1u << 20;
  short* qbf = (short*)(ws + 0);        // 8 MB  (reused as attn out)
  short* kbf = (short*)(ws + 8 * MB);   // 8 MB
  short* vbf = (short*)(ws + 16 * MB);  // 8 MB
  short* Wqb = (short*)(ws + 24 * MB);  // 2 MB
  short* Wkb = (short*)(ws + 26 * MB);
  short* Wvb = (short*)(ws + 28 * MB);
  short* Wob = (short*)(ws + 30 * MB);
  short* Qh  = (short*)(ws + 32 * MB);  // 8 MB [B,N,T,DH]
  short* Kh  = (short*)(ws + 40 * MB);  // 8 MB [B,N,T,DH]
  short* Vth = (short*)(ws + 48 * MB);  // 8 MB [B,N,DH,T]
  short* attnb = qbf;                   // alias: qbf dead after proj_qkv

  cvt_all<<<dim3(2048), dim3(256), 0, stream>>>(query, key, value, Wq, Wk, Wv, Wo,
                                                qbf, kbf, vbf, Wqb, Wkb, Wvb, Wob);
  proj_qkv<<<dim3(32, 8, 3), dim3(256), 0, stream>>>(qbf, kbf, vbf, Wqb, Wkb, Wvb,
                                                     bq, bk, bv, Qh, Kh, Vth);
  attn_kernel<<<dim3(8, 64), dim3(256), 0, stream>>>(Qh, Kh, Vth, wts, mask, attnb);
  gemm_out<<<dim3(32, 8), dim3(256), 0, stream>>>(attnb, Wob, bo, (float*)d_out);
}